// Round 26
// baseline (260.199 us; speedup 1.0000x reference)
//
#include <hip/hip_runtime.h>
#include <math.h>
#include <stdint.h>

#define Bsz 8
#define Lsz 8192
#define D 256
#define NROWS (Bsz*Lsz)      // 65536
#define NC 128               // chunks per sequence
#define CL (Lsz/NC)          // 64
#define LN_EPS 1e-6f

typedef float f32x4 __attribute__((ext_vector_type(4)));
typedef short bf16x8 __attribute__((ext_vector_type(8)));

__device__ __forceinline__ float gelu_tanh(float v){
    const float k0 = 0.7978845608028654f;   // sqrt(2/pi)
    const float k1 = 0.044715f;
    float inner = k0 * fmaf(k1*v*v, v, v);
    return 0.5f * v * (1.0f + tanhf(inner));
}
__device__ __forceinline__ uint16_t bf16_rne(float f){
    uint32_t u = __float_as_uint(f);
    return (uint16_t)((u + 0x7fffu + ((u>>16)&1u)) >> 16);
}
__device__ __forceinline__ float bf16_to_f(uint16_t h){
    return __uint_as_float(((uint32_t)h)<<16);
}

// frag-major short index: 16B chunk = (row-tile, k-chunk), lane-row inside.
__device__ __forceinline__ int frag_s(int row, int k, int KC){
    return ((row>>4)*KC + (k>>3))*128 + (row&15)*8 + (k&7);
}
// bu plane DWORD index == frag_s(row, 2h, 64)/2.
__device__ __forceinline__ int bu_dw(int row, int h){
    return ((row>>4)*64 + (h>>2))*64 + (row&15)*4 + (h&3);
}

// ---- prep: split weights to bf16 planes, frag-major ------------------------
// b2 hi-only (stage-1 1-product), b3 hi-only (stage-2 1-product: out error
// ~2^-9*|y3| ~ 3e-3, no downstream amplification; same validated class as b2).
__global__ __launch_bounds__(256)
void k_prep(const float* __restrict__ B_re, const float* __restrict__ B_im,
            const float* __restrict__ C_re, const float* __restrict__ C_im,
            const float* __restrict__ W, const float* __restrict__ ln_scale,
            short* __restrict__ b1_hi, short* __restrict__ b1_lo,
            short* __restrict__ b2_hi,
            short* __restrict__ b3_hi){
    int i = blockIdx.x*256 + threadIdx.x;   // 131072
    {   // b1 [512 n][256 k]
        int n = i >> 8, d = i & 255;
        float v = (n < 256 ? B_re[n*256 + d] : B_im[(n-256)*256 + d]) * ln_scale[d];
        uint16_t hi = bf16_rne(v);
        int o = frag_s(n, d, 32);
        b1_hi[o] = (short)hi;
        b1_lo[o] = (short)bf16_rne(v - bf16_to_f(hi));
    }
    {   // b2 [256 n][512 k], K-interleaved re/im (k=2h re, k=2h+1 -im)
        int n = i >> 9, k = i & 511, h = k >> 1;
        float v = (k & 1) ? -C_im[n*256 + h] : C_re[n*256 + h];
        b2_hi[frag_s(n, k, 64)] = (short)bf16_rne(v);
    }
    if (i < 256*256){   // b3 [256 n][256 k]
        b3_hi[frag_s(i >> 8, i & 255, 32)] = (short)bf16_rne(W[i]);
    }
}

__global__ __launch_bounds__(256)
void k_prep_t(const float* __restrict__ B_re, const float* __restrict__ B_im,
              const float* __restrict__ ln_scale, const float* __restrict__ ln_bias,
              float* __restrict__ t1, float* __restrict__ t2){
    int n = blockIdx.x*256 + threadIdx.x;
    if (n >= 512) return;
    const float* src = (n < 256) ? &B_re[n*256] : &B_im[(n-256)*256];
    float s1 = 0.f, s2 = 0.f;
    for (int d = 0; d < 256; d++){
        float b = src[d];
        s1 = fmaf(ln_scale[d], b, s1);
        s2 = fmaf(ln_bias[d],  b, s2);
    }
    t1[n] = s1; t2[n] = s2;
}

// ---- stats: LN (mu, rstd) + x_hi plane only (2-product GEMM1) --------------
__global__ __launch_bounds__(256)
void k_stats(const float* __restrict__ x, float* __restrict__ mu_arr,
             float* __restrict__ rstd_arr, short* __restrict__ xhi){
    int r0 = blockIdx.x * 16;
    int t = threadIdx.x;
    int wave = t >> 6, lane = t & 63;
    for (int rr = wave; rr < 16; rr += 4){
        int row = r0 + rr;
        const float* xr = x + (size_t)row * D;
        float v[4]; float s = 0.f;
        #pragma unroll
        for (int i=0;i<4;i++){ v[i] = xr[lane + 64*i]; s += v[i]; }
        #pragma unroll
        for (int off=32; off; off>>=1) s += __shfl_xor(s, off);
        float mu = s * (1.0f/D);
        float vs = 0.f;
        #pragma unroll
        for (int i=0;i<4;i++){ float dd = v[i]-mu; vs += dd*dd; }
        #pragma unroll
        for (int off=32; off; off>>=1) vs += __shfl_xor(vs, off);
        float rstd = rsqrtf(vs*(1.0f/D) + LN_EPS);
        if (lane == 0){ mu_arr[row] = mu; rstd_arr[row] = rstd; }
        #pragma unroll
        for (int i=0;i<4;i++){
            int dd = lane + 64*i;
            xhi[frag_s(row, dd, 32)] = (short)bf16_rne(v[i]);
        }
    }
}

// ---- GEMM1: LDS-free register GEMM, 2-deep pipeline, 2-product split -------
__global__ __launch_bounds__(256, 2)
void k_gemm1(const short* __restrict__ Ahi_g,
             const short* __restrict__ Bhi_g, const short* __restrict__ Blo_g,
             const float* __restrict__ mu_arr, const float* __restrict__ rs_arr,
             const float* __restrict__ t1, const float* __restrict__ t2,
             const float* __restrict__ nu_log,
             float* __restrict__ outA, float* __restrict__ outB){
    constexpr int K = 256, KC = K/8, KCS = KC*128, NYB = 4, NT = K/32;
    const int nwg = (int)gridDim.x;               // multiple of 8
    const int bid = ((int)blockIdx.x & 7)*(nwg>>3) + ((int)blockIdx.x >> 3);
    const int wv = threadIdx.x >> 6, lane = threadIdx.x & 63;
    const int lgrp = lane >> 4, lrow = lane & 15;
    const int rt0 = (bid/NYB)*8 + (wv>>1)*4;
    const int nt0 = (bid%NYB)*8 + (wv&1)*4;
    const int abase = (rt0*KC + lgrp)*128 + lrow*8;
    const int bbase = (nt0*KC + lgrp)*128 + lrow*8;

    f32x4 acc[4][4];
    #pragma unroll
    for (int mf=0;mf<4;mf++)
    #pragma unroll
    for (int nf=0;nf<4;nf++) acc[mf][nf] = (f32x4){0.f,0.f,0.f,0.f};

    bf16x8 fa0[4], fb0h[4], fb0l[4];
    bf16x8 fa1[4], fb1h[4], fb1l[4];

#define LDSET(S, KT) do{ const int ko_ = (KT)*512; \
    _Pragma("unroll") \
    for (int nf=0;nf<4;nf++){ \
        fb##S##h[nf] = *(const bf16x8*)&Bhi_g[bbase + nf*KCS + ko_]; \
        fb##S##l[nf] = *(const bf16x8*)&Blo_g[bbase + nf*KCS + ko_]; } \
    _Pragma("unroll") \
    for (int mf=0;mf<4;mf++){ \
        fa##S[mf] = *(const bf16x8*)&Ahi_g[abase + mf*KCS + ko_]; } \
}while(0)

#define MMSET(S) do{ \
    __builtin_amdgcn_s_setprio(1); \
    _Pragma("unroll") \
    for (int mf=0;mf<4;mf++) \
    _Pragma("unroll") \
    for (int nf=0;nf<4;nf++){ \
        acc[mf][nf] = __builtin_amdgcn_mfma_f32_16x16x32_bf16(fa##S[mf], fb##S##h[nf], acc[mf][nf],0,0,0); \
        acc[mf][nf] = __builtin_amdgcn_mfma_f32_16x16x32_bf16(fa##S[mf], fb##S##l[nf], acc[mf][nf],0,0,0); } \
    __builtin_amdgcn_s_setprio(0); \
}while(0)

    LDSET(0, 0);
    #pragma unroll 1
    for (int kt = 0; kt < NT; kt += 2){
        LDSET(1, kt+1);
        MMSET(0);
        if (kt+2 < NT) LDSET(0, kt+2);
        MMSET(1);
    }
#undef LDSET
#undef MMSET

    const int mrow0 = (bid/NYB)*128 + (wv>>1)*64;
    const int col0  = (bid%NYB)*128 + (wv&1)*64;
    #pragma unroll
    for (int nf=0; nf<4; nf++){
        const int col = col0 + nf*16 + lrow;      // 0..511
        float gam = sqrtf(1.0f - expf(-2.0f*expf(nu_log[col & 255])));
        float t1v = t1[col], t2v = t2[col];
        float* dst = (col < 256) ? outA : outB;
        int c2 = col & 255;
        #pragma unroll
        for (int mf=0;mf<4;mf++){
            #pragma unroll
            for (int j=0;j<4;j++){
                int row = mrow0 + mf*16 + lgrp*4 + j;
                float rs = rs_arr[row], muv = mu_arr[row];
                dst[bu_dw(row, c2)] = gam * (rs*acc[mf][nf][j] - rs*muv*t1v + t2v);
            }
        }
    }
}

// ---- fused SCAN + GEMM2 + GEMM3: stage1 1-product, stage2 1-product --------
__global__ __launch_bounds__(256, 2)
void k_fuse_sgg(const float* __restrict__ bu_re, const float* __restrict__ bu_im,
                const float* __restrict__ p_re, const float* __restrict__ p_im,
                const float* __restrict__ nu_log, const float* __restrict__ theta_log,
                const short* __restrict__ B2hi,
                const short* __restrict__ B3hi,
                const float* __restrict__ x,
                const float* __restrict__ mu_arr, const float* __restrict__ rs_arr,
                const float* __restrict__ ln_scale, const float* __restrict__ ln_bias,
                const float* __restrict__ d_skip, const float* __restrict__ bvec,
                float* __restrict__ out){
    constexpr int KCS1 = 64*128;                  // B2 shorts per n-tile (KC1=64)
    constexpr int NT1  = 16;                      // K=512 / 32
    constexpr int KCS3 = 32*128, NT2 = 8;         // stage2: K=256
    __shared__ __align__(16) short Hbuf[256*136]; // 69632 B; Gh aliases [0,32KB)
    const int t = threadIdx.x;
    const int bid = blockIdx.x;                   // 1024 blocks
    const int r0 = bid*64;

    // ---- phase A: scan (channel = t) ----
    {
        const int b = bid >> 7, c = bid & 127;
        float en = expf(nu_log[t]);
        float mag = expf(-en), th = expf(theta_log[t]);
        float lam_re = mag*cosf(th), lam_im = mag*sinf(th);
        int pidx = (c*Bsz + b)*D + t;
        float sr = p_re[pidx], si = p_im[pidx];
        uint32_t* H32 = (uint32_t*)Hbuf;
        #pragma unroll 4
        for (int tt=0; tt<64; tt++){
            int o = bu_dw(r0+tt, t);
            float ur = bu_re[o], ui = bu_im[o];
            float nsr = fmaf(lam_re, sr, fmaf(-lam_im, si, ur));
            float nsi = fmaf(lam_re, si, fmaf( lam_im, sr, ui));
            sr = nsr; si = nsi;
            uint16_t rh = bf16_rne(sr), ih = bf16_rne(si);
            H32[((tt>>4)*64 + (t>>2))*68 + (tt&15)*4 + (t&3)] =
                (uint32_t)rh | ((uint32_t)ih << 16);
        }
    }
    __syncthreads();

    // ---- phase B: stage1 GEMM (A from LDS, B2hi global, 1-product) ----
    const int wv = t >> 6, lane = t & 63;
    const int lgrp = lane >> 4, lrow = lane & 15;
    const int bbase = ((wv*4)*64 + lgrp)*128 + lrow*8;

    f32x4 acc[4][4];
    #pragma unroll
    for (int mf=0;mf<4;mf++)
    #pragma unroll
    for (int nf=0;nf<4;nf++) acc[mf][nf] = (f32x4){0.f,0.f,0.f,0.f};

    bf16x8 fa0[4], fb0h[4];
    bf16x8 fa1[4], fb1h[4];

#define LDB(S, KT) do{ const int ko_ = (KT)*512; \
    _Pragma("unroll") \
    for (int nf=0;nf<4;nf++){ \
        fb##S##h[nf] = *(const bf16x8*)&B2hi[bbase + nf*KCS1 + ko_]; } \
}while(0)

#define LDA(S, KT) do{ \
    _Pragma("unroll") \
    for (int mf=0;mf<4;mf++){ \
        fa##S[mf] = *(const bf16x8*)&Hbuf[(mf*64 + (KT)*4 + lgrp)*136 + lrow*8]; } \
}while(0)

#define MM1(S) do{ \
    __builtin_amdgcn_s_setprio(1); \
    _Pragma("unroll") \
    for (int mf=0;mf<4;mf++) \
    _Pragma("unroll") \
    for (int nf=0;nf<4;nf++){ \
        acc[mf][nf] = __builtin_amdgcn_mfma_f32_16x16x32_bf16(fa##S[mf], fb##S##h[nf], acc[mf][nf],0,0,0); } \
    __builtin_amdgcn_s_setprio(0); \
}while(0)

    LDB(0, 0);
    #pragma unroll 1
    for (int kt = 0; kt < NT1; kt += 2){
        LDB(1, kt+1);
        LDA(0, kt);
        MM1(0);
        if (kt+2 < NT1) LDB(0, kt+2);
        LDA(1, kt+1);
        MM1(1);
    }
#undef LDB
#undef LDA
#undef MM1
    __syncthreads();                   // all waves done reading H

    // ---- epilogue 1: gelu(y + Dskip*xn) -> g_hi into LDS (aliases H) ----
    #pragma unroll
    for (int nf=0; nf<4; nf++){
        const int col = wv*64 + nf*16 + lrow;     // 0..255
        float dsk = d_skip[col], sc = ln_scale[col], bi = ln_bias[col];
        #pragma unroll
        for (int mf=0;mf<4;mf++){
            #pragma unroll
            for (int j=0;j<4;j++){
                int rl = mf*16 + lgrp*4 + j;
                int row = r0 + rl;
                size_t idx = (size_t)row*256 + col;
                float rs = rs_arr[row], muv = mu_arr[row];
                float xn = (x[idx] - muv)*rs*sc + bi;
                float g = gelu_tanh(acc[mf][nf][j] + dsk*xn);
                int o = (mf*32 + (col>>3))*128 + (lgrp*4+j)*8 + (col&7);
                Hbuf[o] = (short)bf16_rne(g);
            }
        }
    }
    __syncthreads();

    // ---- phase C: stage2 out = g_hi W_hi^T + b + x (1-product) ----
    #pragma unroll
    for (int mf=0;mf<4;mf++)
    #pragma unroll
    for (int nf=0;nf<4;nf++) acc[mf][nf] = (f32x4){0.f,0.f,0.f,0.f};

    const int b3base = ((wv*4)*32 + lgrp)*128 + lrow*8;
    #pragma unroll 1
    for (int kt = 0; kt < NT2; ++kt){
        const int ko = kt*512;
        bf16x8 bh[4], ah[4];
        #pragma unroll
        for (int nf=0;nf<4;nf++){
            bh[nf] = *(const bf16x8*)&B3hi[b3base + nf*KCS3 + ko];
        }
        #pragma unroll
        for (int mf=0;mf<4;mf++){
            const int o = (mf*32 + kt*4 + lgrp)*128 + lrow*8;
            ah[mf] = *(const bf16x8*)&Hbuf[o];
        }
        __builtin_amdgcn_s_setprio(1);
        #pragma unroll
        for (int mf=0;mf<4;mf++)
        #pragma unroll
        for (int nf=0;nf<4;nf++){
            acc[mf][nf] = __builtin_amdgcn_mfma_f32_16x16x32_bf16(ah[mf], bh[nf], acc[mf][nf],0,0,0);
        }
        __builtin_amdgcn_s_setprio(0);
    }

    #pragma unroll
    for (int nf=0; nf<4; nf++){
        const int col = wv*64 + nf*16 + lrow;
        float bb = bvec[col];
        #pragma unroll
        for (int mf=0;mf<4;mf++){
            #pragma unroll
            for (int j=0;j<4;j++){
                int row = r0 + mf*16 + lgrp*4 + j;
                size_t idx = (size_t)row*256 + col;
                out[idx] = acc[mf][nf][j] + bb + x[idx];
            }
        }
    }
}

// ---- scan kernels (chunk sums + fp64 combine) -------------------------------
__global__ __launch_bounds__(256)
void k_scan_local(const float* __restrict__ nu_log, const float* __restrict__ theta_log,
                  const float* __restrict__ bu_re, const float* __restrict__ bu_im,
                  float* __restrict__ e_re, float* __restrict__ e_im){
    int h = threadIdx.x;
    int bc = blockIdx.x;
    int b = bc / NC, c = bc % NC;
    float en = expf(nu_log[h]);
    float mag = expf(-en), th = expf(theta_log[h]);
    float lam_re = mag * cosf(th), lam_im = mag * sinf(th);
    int row0 = b*Lsz + c*CL;
    float sr = 0.f, si = 0.f;
    #pragma unroll 4
    for (int tt=0; tt<CL; tt++){
        int o = bu_dw(row0 + tt, h);
        float ur = bu_re[o], ui = bu_im[o];
        float nsr = fmaf(lam_re, sr, fmaf(-lam_im, si, ur));
        float nsi = fmaf(lam_re, si, fmaf( lam_im, sr, ui));
        sr = nsr; si = nsi;
    }
    e_re[(c*Bsz + b)*D + h] = sr;
    e_im[(c*Bsz + b)*D + h] = si;
}

__global__ __launch_bounds__(256)
void k_scan_combine(const float* __restrict__ nu_log, const float* __restrict__ theta_log,
                    const float* __restrict__ e_re, const float* __restrict__ e_im,
                    float* __restrict__ p_re, float* __restrict__ p_im){
    int h = threadIdx.x;
    int b = blockIdx.x;
    double en = exp((double)nu_log[h]);
    double th = exp((double)theta_log[h]);
    double mag = exp(-en);
    double lr = mag*cos(th), li = mag*sin(th);
    double ar = 1.0, ai = 0.0;               // lam^CL
    for (int i=0;i<CL;i++){
        double nr = ar*lr - ai*li;
        double ni = ar*li + ai*lr;
        ar = nr; ai = ni;
    }
    double sr = 0.0, si = 0.0;
    for (int c=0;c<NC;c++){
        int idx = (c*Bsz + b)*D + h;
        p_re[idx] = (float)sr; p_im[idx] = (float)si;
        double er = e_re[idx], ei = e_im[idx];
        double nr = ar*sr - ai*si + er;
        double ni = ar*si + ai*sr + ei;
        sr = nr; si = ni;
    }
}

extern "C" void kernel_launch(void* const* d_in, const int* in_sizes, int n_in,
                              void* d_out, int out_size, void* d_ws, size_t ws_size,
                              hipStream_t stream){
    const float* x         = (const float*)d_in[0];
    const float* ln_scale  = (const float*)d_in[1];
    const float* ln_bias   = (const float*)d_in[2];
    const float* nu_log    = (const float*)d_in[3];
    const float* theta_log = (const float*)d_in[4];
    const float* B_re      = (const float*)d_in[5];
    const float* B_im      = (const float*)d_in[6];
    const float* C_re      = (const float*)d_in[7];
    const float* C_im      = (const float*)d_in[8];
    const float* D_skip    = (const float*)d_in[9];
    const float* W         = (const float*)d_in[10];
    const float* bvec      = (const float*)d_in[11];
    float* out = (float*)d_out;

    char* base = (char*)d_ws;
    size_t off = 0;
    auto alloc = [&](size_t bytes)->char*{
        char* p = base + off;
        off += (bytes + 255) & ~(size_t)255;
        return p;
    };
    float*  bu_re = (float*)alloc((size_t)NROWS*D*4);
    float*  bu_im = (float*)alloc((size_t)NROWS*D*4);
    short*  xg_hi = (short*)alloc((size_t)NROWS*D*2);   // xhi (GEMM1 A)
    float*  mu_a  = (float*)alloc((size_t)NROWS*4);
    float*  rs_a  = (float*)alloc((size_t)NROWS*4);
    float*  e_re  = (float*)alloc((size_t)NC*Bsz*D*4);
    float*  e_im  = (float*)alloc((size_t)NC*Bsz*D*4);
    float*  p_re  = (float*)alloc((size_t)NC*Bsz*D*4);
    float*  p_im  = (float*)alloc((size_t)NC*Bsz*D*4);
    float*  t1    = (float*)alloc(512*4);
    float*  t2    = (float*)alloc(512*4);
    short*  b1_hi = (short*)alloc(512*256*2);
    short*  b1_lo = (short*)alloc(512*256*2);
    short*  b2_hi = (short*)alloc(256*512*2);
    short*  b3_hi = (short*)alloc(256*256*2);

    k_prep<<<512, 256, 0, stream>>>(B_re, B_im, C_re, C_im, W, ln_scale,
                                    b1_hi, b1_lo, b2_hi, b3_hi);
    k_prep_t<<<2, 256, 0, stream>>>(B_re, B_im, ln_scale, ln_bias, t1, t2);
    k_stats<<<NROWS/16, 256, 0, stream>>>(x, mu_a, rs_a, xg_hi);

    // GEMM1: Bu = gamma*(LN(x) @ B1^T)   (N=512: cols 0-255 re, 256-511 im)
    k_gemm1<<<(NROWS/128)*4, 256, 0, stream>>>(
        xg_hi, b1_hi, b1_lo, mu_a, rs_a, t1, t2, nu_log, bu_re, bu_im);

    k_scan_local<<<Bsz*NC, 256, 0, stream>>>(nu_log, theta_log, bu_re, bu_im, e_re, e_im);
    k_scan_combine<<<Bsz, 256, 0, stream>>>(nu_log, theta_log, e_re, e_im, p_re, p_im);

    // fused scan + GEMM2 + GEMM3
    k_fuse_sgg<<<NROWS/64, 256, 0, stream>>>(
        bu_re, bu_im, p_re, p_im, nu_log, theta_log,
        b2_hi, b3_hi,
        x, mu_a, rs_a, ln_scale, ln_bias, D_skip, bvec, out);
}

// Round 27
// 246.487 us; speedup vs baseline: 1.0556x; 1.0556x over previous
//
#include <hip/hip_runtime.h>
#include <math.h>
#include <stdint.h>

#define Bsz 8
#define Lsz 8192
#define D 256
#define NROWS (Bsz*Lsz)      // 65536
#define NC 128               // chunks per sequence
#define CL (Lsz/NC)          // 64
#define LN_EPS 1e-6f

typedef float f32x4 __attribute__((ext_vector_type(4)));
typedef short bf16x8 __attribute__((ext_vector_type(8)));

__device__ __forceinline__ float gelu_tanh(float v){
    const float k0 = 0.7978845608028654f;   // sqrt(2/pi)
    const float k1 = 0.044715f;
    float inner = k0 * fmaf(k1*v*v, v, v);
    return 0.5f * v * (1.0f + tanhf(inner));
}
__device__ __forceinline__ uint16_t bf16_rne(float f){
    uint32_t u = __float_as_uint(f);
    return (uint16_t)((u + 0x7fffu + ((u>>16)&1u)) >> 16);
}
__device__ __forceinline__ float bf16_to_f(uint16_t h){
    return __uint_as_float(((uint32_t)h)<<16);
}

// frag-major short index: 16B chunk = (row-tile, k-chunk), lane-row inside.
__device__ __forceinline__ int frag_s(int row, int k, int KC){
    return ((row>>4)*KC + (k>>3))*128 + (row&15)*8 + (k&7);
}
// bu plane DWORD index == frag_s(row, 2h, 64)/2.
__device__ __forceinline__ int bu_dw(int row, int h){
    return ((row>>4)*64 + (h>>2))*64 + (row&15)*4 + (h&3);
}

// ---- prep: bf16 hi planes only, frag-major ---------------------------------
// All GEMMs are now 1-product bf16 (b1/b2/b3 hi-only). Error budget: each
// drop adds ~2^-9 relative noise; for b1 the gamma normalization cancels the
// scan's sqrt-variance amplification. Four prior cuts left absmax at 0.03125.
__global__ __launch_bounds__(256)
void k_prep(const float* __restrict__ B_re, const float* __restrict__ B_im,
            const float* __restrict__ C_re, const float* __restrict__ C_im,
            const float* __restrict__ W, const float* __restrict__ ln_scale,
            short* __restrict__ b1_hi,
            short* __restrict__ b2_hi,
            short* __restrict__ b3_hi){
    int i = blockIdx.x*256 + threadIdx.x;   // 131072
    {   // b1 [512 n][256 k]
        int n = i >> 8, d = i & 255;
        float v = (n < 256 ? B_re[n*256 + d] : B_im[(n-256)*256 + d]) * ln_scale[d];
        b1_hi[frag_s(n, d, 32)] = (short)bf16_rne(v);
    }
    {   // b2 [256 n][512 k], K-interleaved re/im (k=2h re, k=2h+1 -im)
        int n = i >> 9, k = i & 511, h = k >> 1;
        float v = (k & 1) ? -C_im[n*256 + h] : C_re[n*256 + h];
        b2_hi[frag_s(n, k, 64)] = (short)bf16_rne(v);
    }
    if (i < 256*256){   // b3 [256 n][256 k]
        b3_hi[frag_s(i >> 8, i & 255, 32)] = (short)bf16_rne(W[i]);
    }
}

__global__ __launch_bounds__(256)
void k_prep_t(const float* __restrict__ B_re, const float* __restrict__ B_im,
              const float* __restrict__ ln_scale, const float* __restrict__ ln_bias,
              float* __restrict__ t1, float* __restrict__ t2){
    int n = blockIdx.x*256 + threadIdx.x;
    if (n >= 512) return;
    const float* src = (n < 256) ? &B_re[n*256] : &B_im[(n-256)*256];
    float s1 = 0.f, s2 = 0.f;
    for (int d = 0; d < 256; d++){
        float b = src[d];
        s1 = fmaf(ln_scale[d], b, s1);
        s2 = fmaf(ln_bias[d],  b, s2);
    }
    t1[n] = s1; t2[n] = s2;
}

// ---- stats: LN (mu, rstd) + x_hi plane -------------------------------------
__global__ __launch_bounds__(256)
void k_stats(const float* __restrict__ x, float* __restrict__ mu_arr,
             float* __restrict__ rstd_arr, short* __restrict__ xhi){
    int r0 = blockIdx.x * 16;
    int t = threadIdx.x;
    int wave = t >> 6, lane = t & 63;
    for (int rr = wave; rr < 16; rr += 4){
        int row = r0 + rr;
        const float* xr = x + (size_t)row * D;
        float v[4]; float s = 0.f;
        #pragma unroll
        for (int i=0;i<4;i++){ v[i] = xr[lane + 64*i]; s += v[i]; }
        #pragma unroll
        for (int off=32; off; off>>=1) s += __shfl_xor(s, off);
        float mu = s * (1.0f/D);
        float vs = 0.f;
        #pragma unroll
        for (int i=0;i<4;i++){ float dd = v[i]-mu; vs += dd*dd; }
        #pragma unroll
        for (int off=32; off; off>>=1) vs += __shfl_xor(vs, off);
        float rstd = rsqrtf(vs*(1.0f/D) + LN_EPS);
        if (lane == 0){ mu_arr[row] = mu; rstd_arr[row] = rstd; }
        #pragma unroll
        for (int i=0;i<4;i++){
            int dd = lane + 64*i;
            xhi[frag_s(row, dd, 32)] = (short)bf16_rne(v[i]);
        }
    }
}

// ---- GEMM1: LDS-free register GEMM, 2-deep pipeline, 1-product -------------
__global__ __launch_bounds__(256, 2)
void k_gemm1(const short* __restrict__ Ahi_g,
             const short* __restrict__ Bhi_g,
             const float* __restrict__ mu_arr, const float* __restrict__ rs_arr,
             const float* __restrict__ t1, const float* __restrict__ t2,
             const float* __restrict__ nu_log,
             float* __restrict__ outA, float* __restrict__ outB){
    constexpr int K = 256, KC = K/8, KCS = KC*128, NYB = 4, NT = K/32;
    const int nwg = (int)gridDim.x;               // multiple of 8
    const int bid = ((int)blockIdx.x & 7)*(nwg>>3) + ((int)blockIdx.x >> 3);
    const int wv = threadIdx.x >> 6, lane = threadIdx.x & 63;
    const int lgrp = lane >> 4, lrow = lane & 15;
    const int rt0 = (bid/NYB)*8 + (wv>>1)*4;
    const int nt0 = (bid%NYB)*8 + (wv&1)*4;
    const int abase = (rt0*KC + lgrp)*128 + lrow*8;
    const int bbase = (nt0*KC + lgrp)*128 + lrow*8;

    f32x4 acc[4][4];
    #pragma unroll
    for (int mf=0;mf<4;mf++)
    #pragma unroll
    for (int nf=0;nf<4;nf++) acc[mf][nf] = (f32x4){0.f,0.f,0.f,0.f};

    bf16x8 fa0[4], fb0[4];
    bf16x8 fa1[4], fb1[4];

#define LDSET(S, KT) do{ const int ko_ = (KT)*512; \
    _Pragma("unroll") \
    for (int nf=0;nf<4;nf++){ \
        fb##S[nf] = *(const bf16x8*)&Bhi_g[bbase + nf*KCS + ko_]; } \
    _Pragma("unroll") \
    for (int mf=0;mf<4;mf++){ \
        fa##S[mf] = *(const bf16x8*)&Ahi_g[abase + mf*KCS + ko_]; } \
}while(0)

#define MMSET(S) do{ \
    __builtin_amdgcn_s_setprio(1); \
    _Pragma("unroll") \
    for (int mf=0;mf<4;mf++) \
    _Pragma("unroll") \
    for (int nf=0;nf<4;nf++){ \
        acc[mf][nf] = __builtin_amdgcn_mfma_f32_16x16x32_bf16(fa##S[mf], fb##S[nf], acc[mf][nf],0,0,0); } \
    __builtin_amdgcn_s_setprio(0); \
}while(0)

    LDSET(0, 0);
    #pragma unroll 1
    for (int kt = 0; kt < NT; kt += 2){
        LDSET(1, kt+1);
        MMSET(0);
        if (kt+2 < NT) LDSET(0, kt+2);
        MMSET(1);
    }
#undef LDSET
#undef MMSET

    const int mrow0 = (bid/NYB)*128 + (wv>>1)*64;
    const int col0  = (bid%NYB)*128 + (wv&1)*64;
    #pragma unroll
    for (int nf=0; nf<4; nf++){
        const int col = col0 + nf*16 + lrow;      // 0..511
        float gam = sqrtf(1.0f - expf(-2.0f*expf(nu_log[col & 255])));
        float t1v = t1[col], t2v = t2[col];
        float* dst = (col < 256) ? outA : outB;
        int c2 = col & 255;
        #pragma unroll
        for (int mf=0;mf<4;mf++){
            #pragma unroll
            for (int j=0;j<4;j++){
                int row = mrow0 + mf*16 + lgrp*4 + j;
                float rs = rs_arr[row], muv = mu_arr[row];
                dst[bu_dw(row, c2)] = gam * (rs*acc[mf][nf][j] - rs*muv*t1v + t2v);
            }
        }
    }
}

// ---- fused SCAN + GEMM2 + GEMM3: stage1 1-product, stage2 1-product --------
__global__ __launch_bounds__(256, 2)
void k_fuse_sgg(const float* __restrict__ bu_re, const float* __restrict__ bu_im,
                const float* __restrict__ p_re, const float* __restrict__ p_im,
                const float* __restrict__ nu_log, const float* __restrict__ theta_log,
                const short* __restrict__ B2hi,
                const short* __restrict__ B3hi,
                const float* __restrict__ x,
                const float* __restrict__ mu_arr, const float* __restrict__ rs_arr,
                const float* __restrict__ ln_scale, const float* __restrict__ ln_bias,
                const float* __restrict__ d_skip, const float* __restrict__ bvec,
                float* __restrict__ out){
    constexpr int KCS1 = 64*128;                  // B2 shorts per n-tile (KC1=64)
    constexpr int NT1  = 16;                      // K=512 / 32
    constexpr int KCS3 = 32*128, NT2 = 8;         // stage2: K=256
    __shared__ __align__(16) short Hbuf[256*136]; // 69632 B; Gh aliases [0,32KB)
    const int t = threadIdx.x;
    const int bid = blockIdx.x;                   // 1024 blocks
    const int r0 = bid*64;

    // ---- phase A: scan (channel = t) ----
    {
        const int b = bid >> 7, c = bid & 127;
        float en = expf(nu_log[t]);
        float mag = expf(-en), th = expf(theta_log[t]);
        float lam_re = mag*cosf(th), lam_im = mag*sinf(th);
        int pidx = (c*Bsz + b)*D + t;
        float sr = p_re[pidx], si = p_im[pidx];
        uint32_t* H32 = (uint32_t*)Hbuf;
        #pragma unroll 4
        for (int tt=0; tt<64; tt++){
            int o = bu_dw(r0+tt, t);
            float ur = bu_re[o], ui = bu_im[o];
            float nsr = fmaf(lam_re, sr, fmaf(-lam_im, si, ur));
            float nsi = fmaf(lam_re, si, fmaf( lam_im, sr, ui));
            sr = nsr; si = nsi;
            uint16_t rh = bf16_rne(sr), ih = bf16_rne(si);
            H32[((tt>>4)*64 + (t>>2))*68 + (tt&15)*4 + (t&3)] =
                (uint32_t)rh | ((uint32_t)ih << 16);
        }
    }
    __syncthreads();

    // ---- phase B: stage1 GEMM (A from LDS, B2hi global, 1-product) ----
    const int wv = t >> 6, lane = t & 63;
    const int lgrp = lane >> 4, lrow = lane & 15;
    const int bbase = ((wv*4)*64 + lgrp)*128 + lrow*8;

    f32x4 acc[4][4];
    #pragma unroll
    for (int mf=0;mf<4;mf++)
    #pragma unroll
    for (int nf=0;nf<4;nf++) acc[mf][nf] = (f32x4){0.f,0.f,0.f,0.f};

    bf16x8 fa0[4], fb0h[4];
    bf16x8 fa1[4], fb1h[4];

#define LDB(S, KT) do{ const int ko_ = (KT)*512; \
    _Pragma("unroll") \
    for (int nf=0;nf<4;nf++){ \
        fb##S##h[nf] = *(const bf16x8*)&B2hi[bbase + nf*KCS1 + ko_]; } \
}while(0)

#define LDA(S, KT) do{ \
    _Pragma("unroll") \
    for (int mf=0;mf<4;mf++){ \
        fa##S[mf] = *(const bf16x8*)&Hbuf[(mf*64 + (KT)*4 + lgrp)*136 + lrow*8]; } \
}while(0)

#define MM1(S) do{ \
    __builtin_amdgcn_s_setprio(1); \
    _Pragma("unroll") \
    for (int mf=0;mf<4;mf++) \
    _Pragma("unroll") \
    for (int nf=0;nf<4;nf++){ \
        acc[mf][nf] = __builtin_amdgcn_mfma_f32_16x16x32_bf16(fa##S[mf], fb##S##h[nf], acc[mf][nf],0,0,0); } \
    __builtin_amdgcn_s_setprio(0); \
}while(0)

    LDB(0, 0);
    #pragma unroll 1
    for (int kt = 0; kt < NT1; kt += 2){
        LDB(1, kt+1);
        LDA(0, kt);
        MM1(0);
        if (kt+2 < NT1) LDB(0, kt+2);
        LDA(1, kt+1);
        MM1(1);
    }
#undef LDB
#undef LDA
#undef MM1
    __syncthreads();                   // all waves done reading H

    // ---- epilogue 1: gelu(y + Dskip*xn) -> g_hi into LDS (aliases H) ----
    #pragma unroll
    for (int nf=0; nf<4; nf++){
        const int col = wv*64 + nf*16 + lrow;     // 0..255
        float dsk = d_skip[col], sc = ln_scale[col], bi = ln_bias[col];
        #pragma unroll
        for (int mf=0;mf<4;mf++){
            #pragma unroll
            for (int j=0;j<4;j++){
                int rl = mf*16 + lgrp*4 + j;
                int row = r0 + rl;
                size_t idx = (size_t)row*256 + col;
                float rs = rs_arr[row], muv = mu_arr[row];
                float xn = (x[idx] - muv)*rs*sc + bi;
                float g = gelu_tanh(acc[mf][nf][j] + dsk*xn);
                int o = (mf*32 + (col>>3))*128 + (lgrp*4+j)*8 + (col&7);
                Hbuf[o] = (short)bf16_rne(g);
            }
        }
    }
    __syncthreads();

    // ---- phase C: stage2 out = g_hi W_hi^T + b + x (1-product) ----
    #pragma unroll
    for (int mf=0;mf<4;mf++)
    #pragma unroll
    for (int nf=0;nf<4;nf++) acc[mf][nf] = (f32x4){0.f,0.f,0.f,0.f};

    const int b3base = ((wv*4)*32 + lgrp)*128 + lrow*8;
    #pragma unroll 1
    for (int kt = 0; kt < NT2; ++kt){
        const int ko = kt*512;
        bf16x8 bh[4], ah[4];
        #pragma unroll
        for (int nf=0;nf<4;nf++){
            bh[nf] = *(const bf16x8*)&B3hi[b3base + nf*KCS3 + ko];
        }
        #pragma unroll
        for (int mf=0;mf<4;mf++){
            const int o = (mf*32 + kt*4 + lgrp)*128 + lrow*8;
            ah[mf] = *(const bf16x8*)&Hbuf[o];
        }
        __builtin_amdgcn_s_setprio(1);
        #pragma unroll
        for (int mf=0;mf<4;mf++)
        #pragma unroll
        for (int nf=0;nf<4;nf++){
            acc[mf][nf] = __builtin_amdgcn_mfma_f32_16x16x32_bf16(ah[mf], bh[nf], acc[mf][nf],0,0,0);
        }
        __builtin_amdgcn_s_setprio(0);
    }

    #pragma unroll
    for (int nf=0; nf<4; nf++){
        const int col = wv*64 + nf*16 + lrow;
        float bb = bvec[col];
        #pragma unroll
        for (int mf=0;mf<4;mf++){
            #pragma unroll
            for (int j=0;j<4;j++){
                int row = r0 + mf*16 + lgrp*4 + j;
                size_t idx = (size_t)row*256 + col;
                out[idx] = acc[mf][nf][j] + bb + x[idx];
            }
        }
    }
}

// ---- scan kernels (chunk sums + fp64 combine) -------------------------------
__global__ __launch_bounds__(256)
void k_scan_local(const float* __restrict__ nu_log, const float* __restrict__ theta_log,
                  const float* __restrict__ bu_re, const float* __restrict__ bu_im,
                  float* __restrict__ e_re, float* __restrict__ e_im){
    int h = threadIdx.x;
    int bc = blockIdx.x;
    int b = bc / NC, c = bc % NC;
    float en = expf(nu_log[h]);
    float mag = expf(-en), th = expf(theta_log[h]);
    float lam_re = mag * cosf(th), lam_im = mag * sinf(th);
    int row0 = b*Lsz + c*CL;
    float sr = 0.f, si = 0.f;
    #pragma unroll 4
    for (int tt=0; tt<CL; tt++){
        int o = bu_dw(row0 + tt, h);
        float ur = bu_re[o], ui = bu_im[o];
        float nsr = fmaf(lam_re, sr, fmaf(-lam_im, si, ur));
        float nsi = fmaf(lam_re, si, fmaf( lam_im, sr, ui));
        sr = nsr; si = nsi;
    }
    e_re[(c*Bsz + b)*D + h] = sr;
    e_im[(c*Bsz + b)*D + h] = si;
}

__global__ __launch_bounds__(256)
void k_scan_combine(const float* __restrict__ nu_log, const float* __restrict__ theta_log,
                    const float* __restrict__ e_re, const float* __restrict__ e_im,
                    float* __restrict__ p_re, float* __restrict__ p_im){
    int h = threadIdx.x;
    int b = blockIdx.x;
    double en = exp((double)nu_log[h]);
    double th = exp((double)theta_log[h]);
    double mag = exp(-en);
    double lr = mag*cos(th), li = mag*sin(th);
    double ar = 1.0, ai = 0.0;               // lam^CL
    for (int i=0;i<CL;i++){
        double nr = ar*lr - ai*li;
        double ni = ar*li + ai*lr;
        ar = nr; ai = ni;
    }
    double sr = 0.0, si = 0.0;
    for (int c=0;c<NC;c++){
        int idx = (c*Bsz + b)*D + h;
        p_re[idx] = (float)sr; p_im[idx] = (float)si;
        double er = e_re[idx], ei = e_im[idx];
        double nr = ar*sr - ai*si + er;
        double ni = ar*si + ai*sr + ei;
        sr = nr; si = ni;
    }
}

extern "C" void kernel_launch(void* const* d_in, const int* in_sizes, int n_in,
                              void* d_out, int out_size, void* d_ws, size_t ws_size,
                              hipStream_t stream){
    const float* x         = (const float*)d_in[0];
    const float* ln_scale  = (const float*)d_in[1];
    const float* ln_bias   = (const float*)d_in[2];
    const float* nu_log    = (const float*)d_in[3];
    const float* theta_log = (const float*)d_in[4];
    const float* B_re      = (const float*)d_in[5];
    const float* B_im      = (const float*)d_in[6];
    const float* C_re      = (const float*)d_in[7];
    const float* C_im      = (const float*)d_in[8];
    const float* D_skip    = (const float*)d_in[9];
    const float* W         = (const float*)d_in[10];
    const float* bvec      = (const float*)d_in[11];
    float* out = (float*)d_out;

    char* base = (char*)d_ws;
    size_t off = 0;
    auto alloc = [&](size_t bytes)->char*{
        char* p = base + off;
        off += (bytes + 255) & ~(size_t)255;
        return p;
    };
    float*  bu_re = (float*)alloc((size_t)NROWS*D*4);
    float*  bu_im = (float*)alloc((size_t)NROWS*D*4);
    short*  xg_hi = (short*)alloc((size_t)NROWS*D*2);   // xhi (GEMM1 A)
    float*  mu_a  = (float*)alloc((size_t)NROWS*4);
    float*  rs_a  = (float*)alloc((size_t)NROWS*4);
    float*  e_re  = (float*)alloc((size_t)NC*Bsz*D*4);
    float*  e_im  = (float*)alloc((size_t)NC*Bsz*D*4);
    float*  p_re  = (float*)alloc((size_t)NC*Bsz*D*4);
    float*  p_im  = (float*)alloc((size_t)NC*Bsz*D*4);
    float*  t1    = (float*)alloc(512*4);
    float*  t2    = (float*)alloc(512*4);
    short*  b1_hi = (short*)alloc(512*256*2);
    short*  b2_hi = (short*)alloc(256*512*2);
    short*  b3_hi = (short*)alloc(256*256*2);

    k_prep<<<512, 256, 0, stream>>>(B_re, B_im, C_re, C_im, W, ln_scale,
                                    b1_hi, b2_hi, b3_hi);
    k_prep_t<<<2, 256, 0, stream>>>(B_re, B_im, ln_scale, ln_bias, t1, t2);
    k_stats<<<NROWS/16, 256, 0, stream>>>(x, mu_a, rs_a, xg_hi);

    // GEMM1: Bu = gamma*(LN(x) @ B1^T)   (N=512: cols 0-255 re, 256-511 im)
    k_gemm1<<<(NROWS/128)*4, 256, 0, stream>>>(
        xg_hi, b1_hi, mu_a, rs_a, t1, t2, nu_log, bu_re, bu_im);

    k_scan_local<<<Bsz*NC, 256, 0, stream>>>(nu_log, theta_log, bu_re, bu_im, e_re, e_im);
    k_scan_combine<<<Bsz, 256, 0, stream>>>(nu_log, theta_log, e_re, e_im, p_re, p_im);

    // fused scan + GEMM2 + GEMM3
    k_fuse_sgg<<<NROWS/64, 256, 0, stream>>>(
        bu_re, bu_im, p_re, p_im, nu_log, theta_log,
        b2_hi, b3_hi,
        x, mu_a, rs_a, ln_scale, ln_bias, D_skip, bvec, out);
}

// Round 29
// 246.408 us; speedup vs baseline: 1.0560x; 1.0003x over previous
//
#include <hip/hip_runtime.h>
#include <math.h>
#include <stdint.h>

#define Bsz 8
#define Lsz 8192
#define D 256
#define NROWS (Bsz*Lsz)      // 65536
#define NC 128               // chunks per sequence
#define CL (Lsz/NC)          // 64
#define LN_EPS 1e-6f

typedef float f32x4 __attribute__((ext_vector_type(4)));
typedef short bf16x8 __attribute__((ext_vector_type(8)));

__device__ __forceinline__ float gelu_tanh(float v){
    const float k0 = 0.7978845608028654f;   // sqrt(2/pi)
    const float k1 = 0.044715f;
    float inner = k0 * fmaf(k1*v*v, v, v);
    return 0.5f * v * (1.0f + tanhf(inner));
}
__device__ __forceinline__ uint16_t bf16_rne(float f){
    uint32_t u = __float_as_uint(f);
    return (uint16_t)((u + 0x7fffu + ((u>>16)&1u)) >> 16);
}
__device__ __forceinline__ float bf16_to_f(uint16_t h){
    return __uint_as_float(((uint32_t)h)<<16);
}

// frag-major short index: 16B chunk = (row-tile, k-chunk), lane-row inside.
__device__ __forceinline__ int frag_s(int row, int k, int KC){
    return ((row>>4)*KC + (k>>3))*128 + (row&15)*8 + (k&7);
}
// bu plane DWORD index == frag_s(row, 2h, 64)/2.
__device__ __forceinline__ int bu_dw(int row, int h){
    return ((row>>4)*64 + (h>>2))*64 + (row&15)*4 + (h&3);
}

// ---- prep: bf16 hi planes only, frag-major ---------------------------------
// All GEMMs are 1-product bf16 (b1/b2/b3 hi-only). Each drop adds ~2^-9
// relative noise; for b1 the gamma normalization cancels the scan's
// sqrt-variance amplification. absmax stays at the output's own bf16
// half-ulp (0.03125).
__global__ __launch_bounds__(256)
void k_prep(const float* __restrict__ B_re, const float* __restrict__ B_im,
            const float* __restrict__ C_re, const float* __restrict__ C_im,
            const float* __restrict__ W, const float* __restrict__ ln_scale,
            short* __restrict__ b1_hi,
            short* __restrict__ b2_hi,
            short* __restrict__ b3_hi){
    int i = blockIdx.x*256 + threadIdx.x;   // 131072
    {   // b1 [512 n][256 k]
        int n = i >> 8, d = i & 255;
        float v = (n < 256 ? B_re[n*256 + d] : B_im[(n-256)*256 + d]) * ln_scale[d];
        b1_hi[frag_s(n, d, 32)] = (short)bf16_rne(v);
    }
    {   // b2 [256 n][512 k], K-interleaved re/im (k=2h re, k=2h+1 -im)
        int n = i >> 9, k = i & 511, h = k >> 1;
        float v = (k & 1) ? -C_im[n*256 + h] : C_re[n*256 + h];
        b2_hi[frag_s(n, k, 64)] = (short)bf16_rne(v);
    }
    if (i < 256*256){   // b3 [256 n][256 k]
        b3_hi[frag_s(i >> 8, i & 255, 32)] = (short)bf16_rne(W[i]);
    }
}

__global__ __launch_bounds__(256)
void k_prep_t(const float* __restrict__ B_re, const float* __restrict__ B_im,
              const float* __restrict__ ln_scale, const float* __restrict__ ln_bias,
              float* __restrict__ t1, float* __restrict__ t2){
    int n = blockIdx.x*256 + threadIdx.x;
    if (n >= 512) return;
    const float* src = (n < 256) ? &B_re[n*256] : &B_im[(n-256)*256];
    float s1 = 0.f, s2 = 0.f;
    for (int d = 0; d < 256; d++){
        float b = src[d];
        s1 = fmaf(ln_scale[d], b, s1);
        s2 = fmaf(ln_bias[d],  b, s2);
    }
    t1[n] = s1; t2[n] = s2;
}

// ---- stats: LN (mu, rstd) + x_hi plane -------------------------------------
__global__ __launch_bounds__(256)
void k_stats(const float* __restrict__ x, float* __restrict__ mu_arr,
             float* __restrict__ rstd_arr, short* __restrict__ xhi){
    int r0 = blockIdx.x * 16;
    int t = threadIdx.x;
    int wave = t >> 6, lane = t & 63;
    for (int rr = wave; rr < 16; rr += 4){
        int row = r0 + rr;
        const float* xr = x + (size_t)row * D;
        float v[4]; float s = 0.f;
        #pragma unroll
        for (int i=0;i<4;i++){ v[i] = xr[lane + 64*i]; s += v[i]; }
        #pragma unroll
        for (int off=32; off; off>>=1) s += __shfl_xor(s, off);
        float mu = s * (1.0f/D);
        float vs = 0.f;
        #pragma unroll
        for (int i=0;i<4;i++){ float dd = v[i]-mu; vs += dd*dd; }
        #pragma unroll
        for (int off=32; off; off>>=1) vs += __shfl_xor(vs, off);
        float rstd = rsqrtf(vs*(1.0f/D) + LN_EPS);
        if (lane == 0){ mu_arr[row] = mu; rstd_arr[row] = rstd; }
        #pragma unroll
        for (int i=0;i<4;i++){
            int dd = lane + 64*i;
            xhi[frag_s(row, dd, 32)] = (short)bf16_rne(v[i]);
        }
    }
}

// ---- GEMM1: LDS-free register GEMM, 2-deep pipeline, 1-product -------------
__global__ __launch_bounds__(256, 2)
void k_gemm1(const short* __restrict__ Ahi_g,
             const short* __restrict__ Bhi_g,
             const float* __restrict__ mu_arr, const float* __restrict__ rs_arr,
             const float* __restrict__ t1, const float* __restrict__ t2,
             const float* __restrict__ nu_log,
             float* __restrict__ outA, float* __restrict__ outB){
    constexpr int K = 256, KC = K/8, KCS = KC*128, NYB = 4, NT = K/32;
    const int nwg = (int)gridDim.x;               // multiple of 8
    const int bid = ((int)blockIdx.x & 7)*(nwg>>3) + ((int)blockIdx.x >> 3);
    const int wv = threadIdx.x >> 6, lane = threadIdx.x & 63;
    const int lgrp = lane >> 4, lrow = lane & 15;
    const int rt0 = (bid/NYB)*8 + (wv>>1)*4;
    const int nt0 = (bid%NYB)*8 + (wv&1)*4;
    const int abase = (rt0*KC + lgrp)*128 + lrow*8;
    const int bbase = (nt0*KC + lgrp)*128 + lrow*8;

    f32x4 acc[4][4];
    #pragma unroll
    for (int mf=0;mf<4;mf++)
    #pragma unroll
    for (int nf=0;nf<4;nf++) acc[mf][nf] = (f32x4){0.f,0.f,0.f,0.f};

    bf16x8 fa0[4], fb0[4];
    bf16x8 fa1[4], fb1[4];

#define LDSET(S, KT) do{ const int ko_ = (KT)*512; \
    _Pragma("unroll") \
    for (int nf=0;nf<4;nf++){ \
        fb##S[nf] = *(const bf16x8*)&Bhi_g[bbase + nf*KCS + ko_]; } \
    _Pragma("unroll") \
    for (int mf=0;mf<4;mf++){ \
        fa##S[mf] = *(const bf16x8*)&Ahi_g[abase + mf*KCS + ko_]; } \
}while(0)

#define MMSET(S) do{ \
    __builtin_amdgcn_s_setprio(1); \
    _Pragma("unroll") \
    for (int mf=0;mf<4;mf++) \
    _Pragma("unroll") \
    for (int nf=0;nf<4;nf++){ \
        acc[mf][nf] = __builtin_amdgcn_mfma_f32_16x16x32_bf16(fa##S[mf], fb##S[nf], acc[mf][nf],0,0,0); } \
    __builtin_amdgcn_s_setprio(0); \
}while(0)

    LDSET(0, 0);
    #pragma unroll 1
    for (int kt = 0; kt < NT; kt += 2){
        LDSET(1, kt+1);
        MMSET(0);
        if (kt+2 < NT) LDSET(0, kt+2);
        MMSET(1);
    }
#undef LDSET
#undef MMSET

    const int mrow0 = (bid/NYB)*128 + (wv>>1)*64;
    const int col0  = (bid%NYB)*128 + (wv&1)*64;
    #pragma unroll
    for (int nf=0; nf<4; nf++){
        const int col = col0 + nf*16 + lrow;      // 0..511
        float gam = sqrtf(1.0f - expf(-2.0f*expf(nu_log[col & 255])));
        float t1v = t1[col], t2v = t2[col];
        float* dst = (col < 256) ? outA : outB;
        int c2 = col & 255;
        #pragma unroll
        for (int mf=0;mf<4;mf++){
            #pragma unroll
            for (int j=0;j<4;j++){
                int row = mrow0 + mf*16 + lgrp*4 + j;
                float rs = rs_arr[row], muv = mu_arr[row];
                dst[bu_dw(row, c2)] = gam * (rs*acc[mf][nf][j] - rs*muv*t1v + t2v);
            }
        }
    }
}

// ---- fused SCAN + GEMM2 + GEMM3: stage1 1-product, stage2 1-product --------
__global__ __launch_bounds__(256, 2)
void k_fuse_sgg(const float* __restrict__ bu_re, const float* __restrict__ bu_im,
                const float* __restrict__ p_re, const float* __restrict__ p_im,
                const float* __restrict__ nu_log, const float* __restrict__ theta_log,
                const short* __restrict__ B2hi,
                const short* __restrict__ B3hi,
                const float* __restrict__ x,
                const float* __restrict__ mu_arr, const float* __restrict__ rs_arr,
                const float* __restrict__ ln_scale, const float* __restrict__ ln_bias,
                const float* __restrict__ d_skip, const float* __restrict__ bvec,
                float* __restrict__ out){
    constexpr int KCS1 = 64*128;                  // B2 shorts per n-tile (KC1=64)
    constexpr int NT1  = 16;                      // K=512 / 32
    constexpr int KCS3 = 32*128, NT2 = 8;         // stage2: K=256
    __shared__ __align__(16) short Hbuf[256*136]; // 69632 B; Gh aliases [0,32KB)
    const int t = threadIdx.x;
    const int bid = blockIdx.x;                   // 1024 blocks
    const int r0 = bid*64;

    // ---- phase A: scan (channel = t) ----
    {
        const int b = bid >> 7, c = bid & 127;
        float en = expf(nu_log[t]);
        float mag = expf(-en), th = expf(theta_log[t]);
        float lam_re = mag*cosf(th), lam_im = mag*sinf(th);
        int pidx = (c*Bsz + b)*D + t;
        float sr = p_re[pidx], si = p_im[pidx];
        uint32_t* H32 = (uint32_t*)Hbuf;
        #pragma unroll 4
        for (int tt=0; tt<64; tt++){
            int o = bu_dw(r0+tt, t);
            float ur = bu_re[o], ui = bu_im[o];
            float nsr = fmaf(lam_re, sr, fmaf(-lam_im, si, ur));
            float nsi = fmaf(lam_re, si, fmaf( lam_im, sr, ui));
            sr = nsr; si = nsi;
            uint16_t rh = bf16_rne(sr), ih = bf16_rne(si);
            H32[((tt>>4)*64 + (t>>2))*68 + (tt&15)*4 + (t&3)] =
                (uint32_t)rh | ((uint32_t)ih << 16);
        }
    }
    __syncthreads();

    // ---- phase B: stage1 GEMM (A from LDS, B2hi global, 1-product) ----
    const int wv = t >> 6, lane = t & 63;
    const int lgrp = lane >> 4, lrow = lane & 15;
    const int bbase = ((wv*4)*64 + lgrp)*128 + lrow*8;

    f32x4 acc[4][4];
    #pragma unroll
    for (int mf=0;mf<4;mf++)
    #pragma unroll
    for (int nf=0;nf<4;nf++) acc[mf][nf] = (f32x4){0.f,0.f,0.f,0.f};

    bf16x8 fa0[4], fb0h[4];
    bf16x8 fa1[4], fb1h[4];

#define LDB(S, KT) do{ const int ko_ = (KT)*512; \
    _Pragma("unroll") \
    for (int nf=0;nf<4;nf++){ \
        fb##S##h[nf] = *(const bf16x8*)&B2hi[bbase + nf*KCS1 + ko_]; } \
}while(0)

#define LDA(S, KT) do{ \
    _Pragma("unroll") \
    for (int mf=0;mf<4;mf++){ \
        fa##S[mf] = *(const bf16x8*)&Hbuf[(mf*64 + (KT)*4 + lgrp)*136 + lrow*8]; } \
}while(0)

#define MM1(S) do{ \
    __builtin_amdgcn_s_setprio(1); \
    _Pragma("unroll") \
    for (int mf=0;mf<4;mf++) \
    _Pragma("unroll") \
    for (int nf=0;nf<4;nf++){ \
        acc[mf][nf] = __builtin_amdgcn_mfma_f32_16x16x32_bf16(fa##S[mf], fb##S##h[nf], acc[mf][nf],0,0,0); } \
    __builtin_amdgcn_s_setprio(0); \
}while(0)

    LDB(0, 0);
    #pragma unroll 1
    for (int kt = 0; kt < NT1; kt += 2){
        LDB(1, kt+1);
        LDA(0, kt);
        MM1(0);
        if (kt+2 < NT1) LDB(0, kt+2);
        LDA(1, kt+1);
        MM1(1);
    }
#undef LDB
#undef LDA
#undef MM1
    __syncthreads();                   // all waves done reading H

    // ---- epilogue 1: gelu(y + Dskip*xn) -> g_hi into LDS (aliases H) ----
    #pragma unroll
    for (int nf=0; nf<4; nf++){
        const int col = wv*64 + nf*16 + lrow;     // 0..255
        float dsk = d_skip[col], sc = ln_scale[col], bi = ln_bias[col];
        #pragma unroll
        for (int mf=0;mf<4;mf++){
            #pragma unroll
            for (int j=0;j<4;j++){
                int rl = mf*16 + lgrp*4 + j;
                int row = r0 + rl;
                size_t idx = (size_t)row*256 + col;
                float rs = rs_arr[row], muv = mu_arr[row];
                float xn = (x[idx] - muv)*rs*sc + bi;
                float g = gelu_tanh(acc[mf][nf][j] + dsk*xn);
                int o = (mf*32 + (col>>3))*128 + (lgrp*4+j)*8 + (col&7);
                Hbuf[o] = (short)bf16_rne(g);
            }
        }
    }
    __syncthreads();

    // ---- phase C: stage2 out = g_hi W_hi^T + b + x (1-product) ----
    #pragma unroll
    for (int mf=0;mf<4;mf++)
    #pragma unroll
    for (int nf=0;nf<4;nf++) acc[mf][nf] = (f32x4){0.f,0.f,0.f,0.f};

    const int b3base = ((wv*4)*32 + lgrp)*128 + lrow*8;
    #pragma unroll 1
    for (int kt = 0; kt < NT2; ++kt){
        const int ko = kt*512;
        bf16x8 bh[4], ah[4];
        #pragma unroll
        for (int nf=0;nf<4;nf++){
            bh[nf] = *(const bf16x8*)&B3hi[b3base + nf*KCS3 + ko];
        }
        #pragma unroll
        for (int mf=0;mf<4;mf++){
            const int o = (mf*32 + kt*4 + lgrp)*128 + lrow*8;
            ah[mf] = *(const bf16x8*)&Hbuf[o];
        }
        __builtin_amdgcn_s_setprio(1);
        #pragma unroll
        for (int mf=0;mf<4;mf++)
        #pragma unroll
        for (int nf=0;nf<4;nf++){
            acc[mf][nf] = __builtin_amdgcn_mfma_f32_16x16x32_bf16(ah[mf], bh[nf], acc[mf][nf],0,0,0);
        }
        __builtin_amdgcn_s_setprio(0);
    }

    #pragma unroll
    for (int nf=0; nf<4; nf++){
        const int col = wv*64 + nf*16 + lrow;
        float bb = bvec[col];
        #pragma unroll
        for (int mf=0;mf<4;mf++){
            #pragma unroll
            for (int j=0;j<4;j++){
                int row = r0 + mf*16 + lgrp*4 + j;
                size_t idx = (size_t)row*256 + col;
                out[idx] = acc[mf][nf][j] + bb + x[idx];
            }
        }
    }
}

// ---- scan kernels (chunk sums + fp64 combine) -------------------------------
__global__ __launch_bounds__(256)
void k_scan_local(const float* __restrict__ nu_log, const float* __restrict__ theta_log,
                  const float* __restrict__ bu_re, const float* __restrict__ bu_im,
                  float* __restrict__ e_re, float* __restrict__ e_im){
    int h = threadIdx.x;
    int bc = blockIdx.x;
    int b = bc / NC, c = bc % NC;
    float en = expf(nu_log[h]);
    float mag = expf(-en), th = expf(theta_log[h]);
    float lam_re = mag * cosf(th), lam_im = mag * sinf(th);
    int row0 = b*Lsz + c*CL;
    float sr = 0.f, si = 0.f;
    #pragma unroll 4
    for (int tt=0; tt<CL; tt++){
        int o = bu_dw(row0 + tt, h);
        float ur = bu_re[o], ui = bu_im[o];
        float nsr = fmaf(lam_re, sr, fmaf(-lam_im, si, ur));
        float nsi = fmaf(lam_re, si, fmaf( lam_im, sr, ui));
        sr = nsr; si = nsi;
    }
    e_re[(c*Bsz + b)*D + h] = sr;
    e_im[(c*Bsz + b)*D + h] = si;
}

__global__ __launch_bounds__(256)
void k_scan_combine(const float* __restrict__ nu_log, const float* __restrict__ theta_log,
                    const float* __restrict__ e_re, const float* __restrict__ e_im,
                    float* __restrict__ p_re, float* __restrict__ p_im){
    int h = threadIdx.x;
    int b = blockIdx.x;
    double en = exp((double)nu_log[h]);
    double th = exp((double)theta_log[h]);
    double mag = exp(-en);
    double lr = mag*cos(th), li = mag*sin(th);
    double ar = 1.0, ai = 0.0;               // lam^CL
    for (int i=0;i<CL;i++){
        double nr = ar*lr - ai*li;
        double ni = ar*li + ai*lr;
        ar = nr; ai = ni;
    }
    double sr = 0.0, si = 0.0;
    for (int c=0;c<NC;c++){
        int idx = (c*Bsz + b)*D + h;
        p_re[idx] = (float)sr; p_im[idx] = (float)si;
        double er = e_re[idx], ei = e_im[idx];
        double nr = ar*sr - ai*si + er;
        double ni = ar*si + ai*sr + ei;
        sr = nr; si = ni;
    }
}

extern "C" void kernel_launch(void* const* d_in, const int* in_sizes, int n_in,
                              void* d_out, int out_size, void* d_ws, size_t ws_size,
                              hipStream_t stream){
    const float* x         = (const float*)d_in[0];
    const float* ln_scale  = (const float*)d_in[1];
    const float* ln_bias   = (const float*)d_in[2];
    const float* nu_log    = (const float*)d_in[3];
    const float* theta_log = (const float*)d_in[4];
    const float* B_re      = (const float*)d_in[5];
    const float* B_im      = (const float*)d_in[6];
    const float* C_re      = (const float*)d_in[7];
    const float* C_im      = (const float*)d_in[8];
    const float* D_skip    = (const float*)d_in[9];
    const float* W         = (const float*)d_in[10];
    const float* bvec      = (const float*)d_in[11];
    float* out = (float*)d_out;

    char* base = (char*)d_ws;
    size_t off = 0;
    auto alloc = [&](size_t bytes)->char*{
        char* p = base + off;
        off += (bytes + 255) & ~(size_t)255;
        return p;
    };
    float*  bu_re = (float*)alloc((size_t)NROWS*D*4);
    float*  bu_im = (float*)alloc((size_t)NROWS*D*4);
    short*  xg_hi = (short*)alloc((size_t)NROWS*D*2);   // xhi (GEMM1 A)
    float*  mu_a  = (float*)alloc((size_t)NROWS*4);
    float*  rs_a  = (float*)alloc((size_t)NROWS*4);
    float*  e_re  = (float*)alloc((size_t)NC*Bsz*D*4);
    float*  e_im  = (float*)alloc((size_t)NC*Bsz*D*4);
    float*  p_re  = (float*)alloc((size_t)NC*Bsz*D*4);
    float*  p_im  = (float*)alloc((size_t)NC*Bsz*D*4);
    float*  t1    = (float*)alloc(512*4);
    float*  t2    = (float*)alloc(512*4);
    short*  b1_hi = (short*)alloc(512*256*2);
    short*  b2_hi = (short*)alloc(256*512*2);
    short*  b3_hi = (short*)alloc(256*256*2);

    k_prep<<<512, 256, 0, stream>>>(B_re, B_im, C_re, C_im, W, ln_scale,
                                    b1_hi, b2_hi, b3_hi);
    k_prep_t<<<2, 256, 0, stream>>>(B_re, B_im, ln_scale, ln_bias, t1, t2);
    k_stats<<<NROWS/16, 256, 0, stream>>>(x, mu_a, rs_a, xg_hi);

    // GEMM1: Bu = gamma*(LN(x) @ B1^T)   (N=512: cols 0-255 re, 256-511 im)
    k_gemm1<<<(NROWS/128)*4, 256, 0, stream>>>(
        xg_hi, b1_hi, mu_a, rs_a, t1, t2, nu_log, bu_re, bu_im);

    k_scan_local<<<Bsz*NC, 256, 0, stream>>>(nu_log, theta_log, bu_re, bu_im, e_re, e_im);
    k_scan_combine<<<Bsz, 256, 0, stream>>>(nu_log, theta_log, e_re, e_im, p_re, p_im);

    // fused scan + GEMM2 + GEMM3
    k_fuse_sgg<<<NROWS/64, 256, 0, stream>>>(
        bu_re, bu_im, p_re, p_im, nu_log, theta_log,
        b2_hi, b3_hi,
        x, mu_a, rs_a, ln_scale, ln_bias, D_skip, bvec, out);
}

// Round 30
// 245.980 us; speedup vs baseline: 1.0578x; 1.0017x over previous
//
#include <hip/hip_runtime.h>
#include <math.h>
#include <stdint.h>

#define Bsz 8
#define Lsz 8192
#define D 256
#define NROWS (Bsz*Lsz)      // 65536
#define NC 128               // chunks per sequence
#define CL (Lsz/NC)          // 64
#define LN_EPS 1e-6f

typedef float f32x4 __attribute__((ext_vector_type(4)));
typedef short bf16x8 __attribute__((ext_vector_type(8)));

__device__ __forceinline__ float gelu_tanh(float v){
    const float k0 = 0.7978845608028654f;   // sqrt(2/pi)
    const float k1 = 0.044715f;
    float inner = k0 * fmaf(k1*v*v, v, v);
    return 0.5f * v * (1.0f + tanhf(inner));
}
__device__ __forceinline__ uint16_t bf16_rne(float f){
    uint32_t u = __float_as_uint(f);
    return (uint16_t)((u + 0x7fffu + ((u>>16)&1u)) >> 16);
}
__device__ __forceinline__ float bf16_to_f(uint16_t h){
    return __uint_as_float(((uint32_t)h)<<16);
}

// frag-major short index: 16B chunk = (row-tile, k-chunk), lane-row inside.
__device__ __forceinline__ int frag_s(int row, int k, int KC){
    return ((row>>4)*KC + (k>>3))*128 + (row&15)*8 + (k&7);
}
// bu plane DWORD index == frag_s(row, 2h, 64)/2.
__device__ __forceinline__ int bu_dw(int row, int h){
    return ((row>>4)*64 + (h>>2))*64 + (row&15)*4 + (h&3);
}

// ---- prep: bf16 hi planes only, frag-major ---------------------------------
__global__ __launch_bounds__(256)
void k_prep(const float* __restrict__ B_re, const float* __restrict__ B_im,
            const float* __restrict__ C_re, const float* __restrict__ C_im,
            const float* __restrict__ W, const float* __restrict__ ln_scale,
            short* __restrict__ b1_hi,
            short* __restrict__ b2_hi,
            short* __restrict__ b3_hi){
    int i = blockIdx.x*256 + threadIdx.x;   // 131072
    {   // b1 [512 n][256 k]
        int n = i >> 8, d = i & 255;
        float v = (n < 256 ? B_re[n*256 + d] : B_im[(n-256)*256 + d]) * ln_scale[d];
        b1_hi[frag_s(n, d, 32)] = (short)bf16_rne(v);
    }
    {   // b2 [256 n][512 k], K-interleaved re/im (k=2h re, k=2h+1 -im)
        int n = i >> 9, k = i & 511, h = k >> 1;
        float v = (k & 1) ? -C_im[n*256 + h] : C_re[n*256 + h];
        b2_hi[frag_s(n, k, 64)] = (short)bf16_rne(v);
    }
    if (i < 256*256){   // b3 [256 n][256 k]
        b3_hi[frag_s(i >> 8, i & 255, 32)] = (short)bf16_rne(W[i]);
    }
}

__global__ __launch_bounds__(256)
void k_prep_t(const float* __restrict__ B_re, const float* __restrict__ B_im,
              const float* __restrict__ ln_scale, const float* __restrict__ ln_bias,
              float* __restrict__ t1, float* __restrict__ t2){
    int n = blockIdx.x*256 + threadIdx.x;
    if (n >= 512) return;
    const float* src = (n < 256) ? &B_re[n*256] : &B_im[(n-256)*256];
    float s1 = 0.f, s2 = 0.f;
    for (int d = 0; d < 256; d++){
        float b = src[d];
        s1 = fmaf(ln_scale[d], b, s1);
        s2 = fmaf(ln_bias[d],  b, s2);
    }
    t1[n] = s1; t2[n] = s2;
}

// ---- stats: LN (mu, rstd) + x_hi plane -------------------------------------
__global__ __launch_bounds__(256)
void k_stats(const float* __restrict__ x, float* __restrict__ mu_arr,
             float* __restrict__ rstd_arr, short* __restrict__ xhi){
    int r0 = blockIdx.x * 16;
    int t = threadIdx.x;
    int wave = t >> 6, lane = t & 63;
    for (int rr = wave; rr < 16; rr += 4){
        int row = r0 + rr;
        const float* xr = x + (size_t)row * D;
        float v[4]; float s = 0.f;
        #pragma unroll
        for (int i=0;i<4;i++){ v[i] = xr[lane + 64*i]; s += v[i]; }
        #pragma unroll
        for (int off=32; off; off>>=1) s += __shfl_xor(s, off);
        float mu = s * (1.0f/D);
        float vs = 0.f;
        #pragma unroll
        for (int i=0;i<4;i++){ float dd = v[i]-mu; vs += dd*dd; }
        #pragma unroll
        for (int off=32; off; off>>=1) vs += __shfl_xor(vs, off);
        float rstd = rsqrtf(vs*(1.0f/D) + LN_EPS);
        if (lane == 0){ mu_arr[row] = mu; rstd_arr[row] = rstd; }
        #pragma unroll
        for (int i=0;i<4;i++){
            int dd = lane + 64*i;
            xhi[frag_s(row, dd, 32)] = (short)bf16_rne(v[i]);
        }
    }
}

// ---- GEMM1: LDS-free register GEMM, 2-deep pipeline, 1-product -------------
// (256,3): 1-product cut freed ~64 frag VGPRs; ~150 unified regs fit the
// 3-wave/EU budget (~168) -> +50% TLP on a latency-bound kernel. Perf-only
// risk (spill -> slower, never incorrect).
__global__ __launch_bounds__(256, 3)
void k_gemm1(const short* __restrict__ Ahi_g,
             const short* __restrict__ Bhi_g,
             const float* __restrict__ mu_arr, const float* __restrict__ rs_arr,
             const float* __restrict__ t1, const float* __restrict__ t2,
             const float* __restrict__ nu_log,
             float* __restrict__ outA, float* __restrict__ outB){
    constexpr int K = 256, KC = K/8, KCS = KC*128, NYB = 4, NT = K/32;
    const int nwg = (int)gridDim.x;               // multiple of 8
    const int bid = ((int)blockIdx.x & 7)*(nwg>>3) + ((int)blockIdx.x >> 3);
    const int wv = threadIdx.x >> 6, lane = threadIdx.x & 63;
    const int lgrp = lane >> 4, lrow = lane & 15;
    const int rt0 = (bid/NYB)*8 + (wv>>1)*4;
    const int nt0 = (bid%NYB)*8 + (wv&1)*4;
    const int abase = (rt0*KC + lgrp)*128 + lrow*8;
    const int bbase = (nt0*KC + lgrp)*128 + lrow*8;

    f32x4 acc[4][4];
    #pragma unroll
    for (int mf=0;mf<4;mf++)
    #pragma unroll
    for (int nf=0;nf<4;nf++) acc[mf][nf] = (f32x4){0.f,0.f,0.f,0.f};

    bf16x8 fa0[4], fb0[4];
    bf16x8 fa1[4], fb1[4];

#define LDSET(S, KT) do{ const int ko_ = (KT)*512; \
    _Pragma("unroll") \
    for (int nf=0;nf<4;nf++){ \
        fb##S[nf] = *(const bf16x8*)&Bhi_g[bbase + nf*KCS + ko_]; } \
    _Pragma("unroll") \
    for (int mf=0;mf<4;mf++){ \
        fa##S[mf] = *(const bf16x8*)&Ahi_g[abase + mf*KCS + ko_]; } \
}while(0)

#define MMSET(S) do{ \
    __builtin_amdgcn_s_setprio(1); \
    _Pragma("unroll") \
    for (int mf=0;mf<4;mf++) \
    _Pragma("unroll") \
    for (int nf=0;nf<4;nf++){ \
        acc[mf][nf] = __builtin_amdgcn_mfma_f32_16x16x32_bf16(fa##S[mf], fb##S[nf], acc[mf][nf],0,0,0); } \
    __builtin_amdgcn_s_setprio(0); \
}while(0)

    LDSET(0, 0);
    #pragma unroll 1
    for (int kt = 0; kt < NT; kt += 2){
        LDSET(1, kt+1);
        MMSET(0);
        if (kt+2 < NT) LDSET(0, kt+2);
        MMSET(1);
    }
#undef LDSET
#undef MMSET

    const int mrow0 = (bid/NYB)*128 + (wv>>1)*64;
    const int col0  = (bid%NYB)*128 + (wv&1)*64;
    #pragma unroll
    for (int nf=0; nf<4; nf++){
        const int col = col0 + nf*16 + lrow;      // 0..511
        float gam = sqrtf(1.0f - expf(-2.0f*expf(nu_log[col & 255])));
        float t1v = t1[col], t2v = t2[col];
        float* dst = (col < 256) ? outA : outB;
        int c2 = col & 255;
        #pragma unroll
        for (int mf=0;mf<4;mf++){
            #pragma unroll
            for (int j=0;j<4;j++){
                int row = mrow0 + mf*16 + lgrp*4 + j;
                float rs = rs_arr[row], muv = mu_arr[row];
                dst[bu_dw(row, c2)] = gam * (rs*acc[mf][nf][j] - rs*muv*t1v + t2v);
            }
        }
    }
}

// ---- fused SCAN + GEMM2 + GEMM3: stage1 1-product, stage2 1-product --------
__global__ __launch_bounds__(256, 2)
void k_fuse_sgg(const float* __restrict__ bu_re, const float* __restrict__ bu_im,
                const float* __restrict__ p_re, const float* __restrict__ p_im,
                const float* __restrict__ nu_log, const float* __restrict__ theta_log,
                const short* __restrict__ B2hi,
                const short* __restrict__ B3hi,
                const float* __restrict__ x,
                const float* __restrict__ mu_arr, const float* __restrict__ rs_arr,
                const float* __restrict__ ln_scale, const float* __restrict__ ln_bias,
                const float* __restrict__ d_skip, const float* __restrict__ bvec,
                float* __restrict__ out){
    constexpr int KCS1 = 64*128;                  // B2 shorts per n-tile (KC1=64)
    constexpr int NT1  = 16;                      // K=512 / 32
    constexpr int KCS3 = 32*128, NT2 = 8;         // stage2: K=256
    __shared__ __align__(16) short Hbuf[256*136]; // 69632 B; Gh aliases [0,32KB)
    const int t = threadIdx.x;
    const int bid = blockIdx.x;                   // 1024 blocks
    const int r0 = bid*64;

    // ---- phase A: scan (channel = t) ----
    {
        const int b = bid >> 7, c = bid & 127;
        float en = expf(nu_log[t]);
        float mag = expf(-en), th = expf(theta_log[t]);
        float lam_re = mag*cosf(th), lam_im = mag*sinf(th);
        int pidx = (c*Bsz + b)*D + t;
        float sr = p_re[pidx], si = p_im[pidx];
        uint32_t* H32 = (uint32_t*)Hbuf;
        #pragma unroll 4
        for (int tt=0; tt<64; tt++){
            int o = bu_dw(r0+tt, t);
            float ur = bu_re[o], ui = bu_im[o];
            float nsr = fmaf(lam_re, sr, fmaf(-lam_im, si, ur));
            float nsi = fmaf(lam_re, si, fmaf( lam_im, sr, ui));
            sr = nsr; si = nsi;
            uint16_t rh = bf16_rne(sr), ih = bf16_rne(si);
            H32[((tt>>4)*64 + (t>>2))*68 + (tt&15)*4 + (t&3)] =
                (uint32_t)rh | ((uint32_t)ih << 16);
        }
    }
    __syncthreads();

    // ---- phase B: stage1 GEMM (A from LDS, B2hi global, 1-product) ----
    const int wv = t >> 6, lane = t & 63;
    const int lgrp = lane >> 4, lrow = lane & 15;
    const int bbase = ((wv*4)*64 + lgrp)*128 + lrow*8;

    f32x4 acc[4][4];
    #pragma unroll
    for (int mf=0;mf<4;mf++)
    #pragma unroll
    for (int nf=0;nf<4;nf++) acc[mf][nf] = (f32x4){0.f,0.f,0.f,0.f};

    bf16x8 fa0[4], fb0h[4];
    bf16x8 fa1[4], fb1h[4];

#define LDB(S, KT) do{ const int ko_ = (KT)*512; \
    _Pragma("unroll") \
    for (int nf=0;nf<4;nf++){ \
        fb##S##h[nf] = *(const bf16x8*)&B2hi[bbase + nf*KCS1 + ko_]; } \
}while(0)

#define LDA(S, KT) do{ \
    _Pragma("unroll") \
    for (int mf=0;mf<4;mf++){ \
        fa##S[mf] = *(const bf16x8*)&Hbuf[(mf*64 + (KT)*4 + lgrp)*136 + lrow*8]; } \
}while(0)

#define MM1(S) do{ \
    __builtin_amdgcn_s_setprio(1); \
    _Pragma("unroll") \
    for (int mf=0;mf<4;mf++) \
    _Pragma("unroll") \
    for (int nf=0;nf<4;nf++){ \
        acc[mf][nf] = __builtin_amdgcn_mfma_f32_16x16x32_bf16(fa##S[mf], fb##S##h[nf], acc[mf][nf],0,0,0); } \
    __builtin_amdgcn_s_setprio(0); \
}while(0)

    LDB(0, 0);
    #pragma unroll 1
    for (int kt = 0; kt < NT1; kt += 2){
        LDB(1, kt+1);
        LDA(0, kt);
        MM1(0);
        if (kt+2 < NT1) LDB(0, kt+2);
        LDA(1, kt+1);
        MM1(1);
    }
#undef LDB
#undef LDA
#undef MM1
    __syncthreads();                   // all waves done reading H

    // ---- epilogue 1: gelu(y + Dskip*xn) -> g_hi into LDS (aliases H) ----
    #pragma unroll
    for (int nf=0; nf<4; nf++){
        const int col = wv*64 + nf*16 + lrow;     // 0..255
        float dsk = d_skip[col], sc = ln_scale[col], bi = ln_bias[col];
        #pragma unroll
        for (int mf=0;mf<4;mf++){
            #pragma unroll
            for (int j=0;j<4;j++){
                int rl = mf*16 + lgrp*4 + j;
                int row = r0 + rl;
                size_t idx = (size_t)row*256 + col;
                float rs = rs_arr[row], muv = mu_arr[row];
                float xn = (x[idx] - muv)*rs*sc + bi;
                float g = gelu_tanh(acc[mf][nf][j] + dsk*xn);
                int o = (mf*32 + (col>>3))*128 + (lgrp*4+j)*8 + (col&7);
                Hbuf[o] = (short)bf16_rne(g);
            }
        }
    }
    __syncthreads();

    // ---- phase C: stage2 out = g_hi W_hi^T + b + x (1-product) ----
    #pragma unroll
    for (int mf=0;mf<4;mf++)
    #pragma unroll
    for (int nf=0;nf<4;nf++) acc[mf][nf] = (f32x4){0.f,0.f,0.f,0.f};

    const int b3base = ((wv*4)*32 + lgrp)*128 + lrow*8;
    #pragma unroll 1
    for (int kt = 0; kt < NT2; ++kt){
        const int ko = kt*512;
        bf16x8 bh[4], ah[4];
        #pragma unroll
        for (int nf=0;nf<4;nf++){
            bh[nf] = *(const bf16x8*)&B3hi[b3base + nf*KCS3 + ko];
        }
        #pragma unroll
        for (int mf=0;mf<4;mf++){
            const int o = (mf*32 + kt*4 + lgrp)*128 + lrow*8;
            ah[mf] = *(const bf16x8*)&Hbuf[o];
        }
        __builtin_amdgcn_s_setprio(1);
        #pragma unroll
        for (int mf=0;mf<4;mf++)
        #pragma unroll
        for (int nf=0;nf<4;nf++){
            acc[mf][nf] = __builtin_amdgcn_mfma_f32_16x16x32_bf16(ah[mf], bh[nf], acc[mf][nf],0,0,0);
        }
        __builtin_amdgcn_s_setprio(0);
    }

    #pragma unroll
    for (int nf=0; nf<4; nf++){
        const int col = wv*64 + nf*16 + lrow;
        float bb = bvec[col];
        #pragma unroll
        for (int mf=0;mf<4;mf++){
            #pragma unroll
            for (int j=0;j<4;j++){
                int row = r0 + mf*16 + lgrp*4 + j;
                size_t idx = (size_t)row*256 + col;
                out[idx] = acc[mf][nf][j] + bb + x[idx];
            }
        }
    }
}

// ---- scan kernels (chunk sums + fp64 combine) -------------------------------
__global__ __launch_bounds__(256)
void k_scan_local(const float* __restrict__ nu_log, const float* __restrict__ theta_log,
                  const float* __restrict__ bu_re, const float* __restrict__ bu_im,
                  float* __restrict__ e_re, float* __restrict__ e_im){
    int h = threadIdx.x;
    int bc = blockIdx.x;
    int b = bc / NC, c = bc % NC;
    float en = expf(nu_log[h]);
    float mag = expf(-en), th = expf(theta_log[h]);
    float lam_re = mag * cosf(th), lam_im = mag * sinf(th);
    int row0 = b*Lsz + c*CL;
    float sr = 0.f, si = 0.f;
    #pragma unroll 4
    for (int tt=0; tt<CL; tt++){
        int o = bu_dw(row0 + tt, h);
        float ur = bu_re[o], ui = bu_im[o];
        float nsr = fmaf(lam_re, sr, fmaf(-lam_im, si, ur));
        float nsi = fmaf(lam_re, si, fmaf( lam_im, sr, ui));
        sr = nsr; si = nsi;
    }
    e_re[(c*Bsz + b)*D + h] = sr;
    e_im[(c*Bsz + b)*D + h] = si;
}

__global__ __launch_bounds__(256)
void k_scan_combine(const float* __restrict__ nu_log, const float* __restrict__ theta_log,
                    const float* __restrict__ e_re, const float* __restrict__ e_im,
                    float* __restrict__ p_re, float* __restrict__ p_im){
    int h = threadIdx.x;
    int b = blockIdx.x;
    double en = exp((double)nu_log[h]);
    double th = exp((double)theta_log[h]);
    double mag = exp(-en);
    double lr = mag*cos(th), li = mag*sin(th);
    double ar = 1.0, ai = 0.0;               // lam^CL
    for (int i=0;i<CL;i++){
        double nr = ar*lr - ai*li;
        double ni = ar*li + ai*lr;
        ar = nr; ai = ni;
    }
    double sr = 0.0, si = 0.0;
    for (int c=0;c<NC;c++){
        int idx = (c*Bsz + b)*D + h;
        p_re[idx] = (float)sr; p_im[idx] = (float)si;
        double er = e_re[idx], ei = e_im[idx];
        double nr = ar*sr - ai*si + er;
        double ni = ar*si + ai*sr + ei;
        sr = nr; si = ni;
    }
}

extern "C" void kernel_launch(void* const* d_in, const int* in_sizes, int n_in,
                              void* d_out, int out_size, void* d_ws, size_t ws_size,
                              hipStream_t stream){
    const float* x         = (const float*)d_in[0];
    const float* ln_scale  = (const float*)d_in[1];
    const float* ln_bias   = (const float*)d_in[2];
    const float* nu_log    = (const float*)d_in[3];
    const float* theta_log = (const float*)d_in[4];
    const float* B_re      = (const float*)d_in[5];
    const float* B_im      = (const float*)d_in[6];
    const float* C_re      = (const float*)d_in[7];
    const float* C_im      = (const float*)d_in[8];
    const float* D_skip    = (const float*)d_in[9];
    const float* W         = (const float*)d_in[10];
    const float* bvec      = (const float*)d_in[11];
    float* out = (float*)d_out;

    char* base = (char*)d_ws;
    size_t off = 0;
    auto alloc = [&](size_t bytes)->char*{
        char* p = base + off;
        off += (bytes + 255) & ~(size_t)255;
        return p;
    };
    float*  bu_re = (float*)alloc((size_t)NROWS*D*4);
    float*  bu_im = (float*)alloc((size_t)NROWS*D*4);
    short*  xg_hi = (short*)alloc((size_t)NROWS*D*2);   // xhi (GEMM1 A)
    float*  mu_a  = (float*)alloc((size_t)NROWS*4);
    float*  rs_a  = (float*)alloc((size_t)NROWS*4);
    float*  e_re  = (float*)alloc((size_t)NC*Bsz*D*4);
    float*  e_im  = (float*)alloc((size_t)NC*Bsz*D*4);
    float*  p_re  = (float*)alloc((size_t)NC*Bsz*D*4);
    float*  p_im  = (float*)alloc((size_t)NC*Bsz*D*4);
    float*  t1    = (float*)alloc(512*4);
    float*  t2    = (float*)alloc(512*4);
    short*  b1_hi = (short*)alloc(512*256*2);
    short*  b2_hi = (short*)alloc(256*512*2);
    short*  b3_hi = (short*)alloc(256*256*2);

    k_prep<<<512, 256, 0, stream>>>(B_re, B_im, C_re, C_im, W, ln_scale,
                                    b1_hi, b2_hi, b3_hi);
    k_prep_t<<<2, 256, 0, stream>>>(B_re, B_im, ln_scale, ln_bias, t1, t2);
    k_stats<<<NROWS/16, 256, 0, stream>>>(x, mu_a, rs_a, xg_hi);

    // GEMM1: Bu = gamma*(LN(x) @ B1^T)   (N=512: cols 0-255 re, 256-511 im)
    k_gemm1<<<(NROWS/128)*4, 256, 0, stream>>>(
        xg_hi, b1_hi, mu_a, rs_a, t1, t2, nu_log, bu_re, bu_im);

    k_scan_local<<<Bsz*NC, 256, 0, stream>>>(nu_log, theta_log, bu_re, bu_im, e_re, e_im);
    k_scan_combine<<<Bsz, 256, 0, stream>>>(nu_log, theta_log, e_re, e_im, p_re, p_im);

    // fused scan + GEMM2 + GEMM3
    k_fuse_sgg<<<NROWS/64, 256, 0, stream>>>(
        bu_re, bu_im, p_re, p_im, nu_log, theta_log,
        b2_hi, b3_hi,
        x, mu_a, rs_a, ln_scale, ln_bias, D_skip, bvec, out);
}

// Round 31
// 242.948 us; speedup vs baseline: 1.0710x; 1.0125x over previous
//
#include <hip/hip_runtime.h>
#include <math.h>
#include <stdint.h>

#define Bsz 8
#define Lsz 8192
#define D 256
#define NROWS (Bsz*Lsz)      // 65536
#define NC 128               // chunks per sequence
#define CL (Lsz/NC)          // 64
#define LN_EPS 1e-6f

typedef float f32x4 __attribute__((ext_vector_type(4)));
typedef short bf16x8 __attribute__((ext_vector_type(8)));

__device__ __forceinline__ float gelu_tanh(float v){
    const float k0 = 0.7978845608028654f;   // sqrt(2/pi)
    const float k1 = 0.044715f;
    float inner = k0 * fmaf(k1*v*v, v, v);
    return 0.5f * v * (1.0f + tanhf(inner));
}
__device__ __forceinline__ uint16_t bf16_rne(float f){
    uint32_t u = __float_as_uint(f);
    return (uint16_t)((u + 0x7fffu + ((u>>16)&1u)) >> 16);
}
__device__ __forceinline__ float bf16_to_f(uint16_t h){
    return __uint_as_float(((uint32_t)h)<<16);
}

// frag-major short index: 16B chunk = (row-tile, k-chunk), lane-row inside.
__device__ __forceinline__ int frag_s(int row, int k, int KC){
    return ((row>>4)*KC + (k>>3))*128 + (row&15)*8 + (k&7);
}
// bu plane DWORD index == frag_s(row, 2h, 64)/2.
__device__ __forceinline__ int bu_dw(int row, int h){
    return ((row>>4)*64 + (h>>2))*64 + (row&15)*4 + (h&3);
}

// ---- prep: bf16 hi planes only, frag-major ---------------------------------
__global__ __launch_bounds__(256)
void k_prep(const float* __restrict__ B_re, const float* __restrict__ B_im,
            const float* __restrict__ C_re, const float* __restrict__ C_im,
            const float* __restrict__ W, const float* __restrict__ ln_scale,
            short* __restrict__ b1_hi,
            short* __restrict__ b2_hi,
            short* __restrict__ b3_hi){
    int i = blockIdx.x*256 + threadIdx.x;   // 131072
    {   // b1 [512 n][256 k]
        int n = i >> 8, d = i & 255;
        float v = (n < 256 ? B_re[n*256 + d] : B_im[(n-256)*256 + d]) * ln_scale[d];
        b1_hi[frag_s(n, d, 32)] = (short)bf16_rne(v);
    }
    {   // b2 [256 n][512 k], K-interleaved re/im (k=2h re, k=2h+1 -im)
        int n = i >> 9, k = i & 511, h = k >> 1;
        float v = (k & 1) ? -C_im[n*256 + h] : C_re[n*256 + h];
        b2_hi[frag_s(n, k, 64)] = (short)bf16_rne(v);
    }
    if (i < 256*256){   // b3 [256 n][256 k]
        b3_hi[frag_s(i >> 8, i & 255, 32)] = (short)bf16_rne(W[i]);
    }
}

__global__ __launch_bounds__(256)
void k_prep_t(const float* __restrict__ B_re, const float* __restrict__ B_im,
              const float* __restrict__ ln_scale, const float* __restrict__ ln_bias,
              float* __restrict__ t1, float* __restrict__ t2){
    int n = blockIdx.x*256 + threadIdx.x;
    if (n >= 512) return;
    const float* src = (n < 256) ? &B_re[n*256] : &B_im[(n-256)*256];
    float s1 = 0.f, s2 = 0.f;
    for (int d = 0; d < 256; d++){
        float b = src[d];
        s1 = fmaf(ln_scale[d], b, s1);
        s2 = fmaf(ln_bias[d],  b, s2);
    }
    t1[n] = s1; t2[n] = s2;
}

// ---- stats: LN (mu, rstd) + x_hi plane -------------------------------------
__global__ __launch_bounds__(256)
void k_stats(const float* __restrict__ x, float* __restrict__ mu_arr,
             float* __restrict__ rstd_arr, short* __restrict__ xhi){
    int r0 = blockIdx.x * 16;
    int t = threadIdx.x;
    int wave = t >> 6, lane = t & 63;
    for (int rr = wave; rr < 16; rr += 4){
        int row = r0 + rr;
        const float* xr = x + (size_t)row * D;
        float v[4]; float s = 0.f;
        #pragma unroll
        for (int i=0;i<4;i++){ v[i] = xr[lane + 64*i]; s += v[i]; }
        #pragma unroll
        for (int off=32; off; off>>=1) s += __shfl_xor(s, off);
        float mu = s * (1.0f/D);
        float vs = 0.f;
        #pragma unroll
        for (int i=0;i<4;i++){ float dd = v[i]-mu; vs += dd*dd; }
        #pragma unroll
        for (int off=32; off; off>>=1) vs += __shfl_xor(vs, off);
        float rstd = rsqrtf(vs*(1.0f/D) + LN_EPS);
        if (lane == 0){ mu_arr[row] = mu; rstd_arr[row] = rstd; }
        #pragma unroll
        for (int i=0;i<4;i++){
            int dd = lane + 64*i;
            xhi[frag_s(row, dd, 32)] = (short)bf16_rne(v[i]);
        }
    }
}

// ---- GEMM1: LDS-free register GEMM, 2-deep pipeline, 1-product -------------
__global__ __launch_bounds__(256, 3)
void k_gemm1(const short* __restrict__ Ahi_g,
             const short* __restrict__ Bhi_g,
             const float* __restrict__ mu_arr, const float* __restrict__ rs_arr,
             const float* __restrict__ t1, const float* __restrict__ t2,
             const float* __restrict__ nu_log,
             float* __restrict__ outA, float* __restrict__ outB){
    constexpr int K = 256, KC = K/8, KCS = KC*128, NYB = 4, NT = K/32;
    const int nwg = (int)gridDim.x;               // multiple of 8
    const int bid = ((int)blockIdx.x & 7)*(nwg>>3) + ((int)blockIdx.x >> 3);
    const int wv = threadIdx.x >> 6, lane = threadIdx.x & 63;
    const int lgrp = lane >> 4, lrow = lane & 15;
    const int rt0 = (bid/NYB)*8 + (wv>>1)*4;
    const int nt0 = (bid%NYB)*8 + (wv&1)*4;
    const int abase = (rt0*KC + lgrp)*128 + lrow*8;
    const int bbase = (nt0*KC + lgrp)*128 + lrow*8;

    f32x4 acc[4][4];
    #pragma unroll
    for (int mf=0;mf<4;mf++)
    #pragma unroll
    for (int nf=0;nf<4;nf++) acc[mf][nf] = (f32x4){0.f,0.f,0.f,0.f};

    bf16x8 fa0[4], fb0[4];
    bf16x8 fa1[4], fb1[4];

#define LDSET(S, KT) do{ const int ko_ = (KT)*512; \
    _Pragma("unroll") \
    for (int nf=0;nf<4;nf++){ \
        fb##S[nf] = *(const bf16x8*)&Bhi_g[bbase + nf*KCS + ko_]; } \
    _Pragma("unroll") \
    for (int mf=0;mf<4;mf++){ \
        fa##S[mf] = *(const bf16x8*)&Ahi_g[abase + mf*KCS + ko_]; } \
}while(0)

#define MMSET(S) do{ \
    __builtin_amdgcn_s_setprio(1); \
    _Pragma("unroll") \
    for (int mf=0;mf<4;mf++) \
    _Pragma("unroll") \
    for (int nf=0;nf<4;nf++){ \
        acc[mf][nf] = __builtin_amdgcn_mfma_f32_16x16x32_bf16(fa##S[mf], fb##S[nf], acc[mf][nf],0,0,0); } \
    __builtin_amdgcn_s_setprio(0); \
}while(0)

    LDSET(0, 0);
    #pragma unroll 1
    for (int kt = 0; kt < NT; kt += 2){
        LDSET(1, kt+1);
        MMSET(0);
        if (kt+2 < NT) LDSET(0, kt+2);
        MMSET(1);
    }
#undef LDSET
#undef MMSET

    const int mrow0 = (bid/NYB)*128 + (wv>>1)*64;
    const int col0  = (bid%NYB)*128 + (wv&1)*64;
    #pragma unroll
    for (int nf=0; nf<4; nf++){
        const int col = col0 + nf*16 + lrow;      // 0..511
        float gam = sqrtf(1.0f - expf(-2.0f*expf(nu_log[col & 255])));
        float t1v = t1[col], t2v = t2[col];
        float* dst = (col < 256) ? outA : outB;
        int c2 = col & 255;
        #pragma unroll
        for (int mf=0;mf<4;mf++){
            #pragma unroll
            for (int j=0;j<4;j++){
                int row = mrow0 + mf*16 + lgrp*4 + j;
                float rs = rs_arr[row], muv = mu_arr[row];
                dst[bu_dw(row, c2)] = gam * (rs*acc[mf][nf][j] - rs*muv*t1v + t2v);
            }
        }
    }
}

// ---- fused SCAN + GEMM2 + GEMM3: stage1 1-product, stage2 1-product --------
__global__ __launch_bounds__(256, 2)
void k_fuse_sgg(const float* __restrict__ bu_re, const float* __restrict__ bu_im,
                const float* __restrict__ p_re, const float* __restrict__ p_im,
                const float* __restrict__ nu_log, const float* __restrict__ theta_log,
                const short* __restrict__ B2hi,
                const short* __restrict__ B3hi,
                const float* __restrict__ x,
                const float* __restrict__ mu_arr, const float* __restrict__ rs_arr,
                const float* __restrict__ ln_scale, const float* __restrict__ ln_bias,
                const float* __restrict__ d_skip, const float* __restrict__ bvec,
                float* __restrict__ out){
    constexpr int KCS1 = 64*128;                  // B2 shorts per n-tile (KC1=64)
    constexpr int NT1  = 16;                      // K=512 / 32
    constexpr int KCS3 = 32*128, NT2 = 8;         // stage2: K=256
    __shared__ __align__(16) short Hbuf[256*136]; // 69632 B; Gh aliases [0,32KB)
    const int t = threadIdx.x;
    const int bid = blockIdx.x;                   // 1024 blocks
    const int r0 = bid*64;

    // ---- phase A: scan (channel = t) ----
    {
        const int b = bid >> 7, c = bid & 127;
        float en = expf(nu_log[t]);
        float mag = expf(-en), th = expf(theta_log[t]);
        float lam_re = mag*cosf(th), lam_im = mag*sinf(th);
        int pidx = (c*Bsz + b)*D + t;
        float sr = p_re[pidx], si = p_im[pidx];
        uint32_t* H32 = (uint32_t*)Hbuf;
        #pragma unroll 4
        for (int tt=0; tt<64; tt++){
            int o = bu_dw(r0+tt, t);
            float ur = bu_re[o], ui = bu_im[o];
            float nsr = fmaf(lam_re, sr, fmaf(-lam_im, si, ur));
            float nsi = fmaf(lam_re, si, fmaf( lam_im, sr, ui));
            sr = nsr; si = nsi;
            uint16_t rh = bf16_rne(sr), ih = bf16_rne(si);
            H32[((tt>>4)*64 + (t>>2))*68 + (tt&15)*4 + (t&3)] =
                (uint32_t)rh | ((uint32_t)ih << 16);
        }
    }
    __syncthreads();

    // ---- phase B: stage1 GEMM (A from LDS, B2hi global, 1-product) ----
    const int wv = t >> 6, lane = t & 63;
    const int lgrp = lane >> 4, lrow = lane & 15;
    const int bbase = ((wv*4)*64 + lgrp)*128 + lrow*8;

    f32x4 acc[4][4];
    #pragma unroll
    for (int mf=0;mf<4;mf++)
    #pragma unroll
    for (int nf=0;nf<4;nf++) acc[mf][nf] = (f32x4){0.f,0.f,0.f,0.f};

    bf16x8 fa0[4], fb0h[4];
    bf16x8 fa1[4], fb1h[4];

#define LDB(S, KT) do{ const int ko_ = (KT)*512; \
    _Pragma("unroll") \
    for (int nf=0;nf<4;nf++){ \
        fb##S##h[nf] = *(const bf16x8*)&B2hi[bbase + nf*KCS1 + ko_]; } \
}while(0)

#define LDA(S, KT) do{ \
    _Pragma("unroll") \
    for (int mf=0;mf<4;mf++){ \
        fa##S[mf] = *(const bf16x8*)&Hbuf[(mf*64 + (KT)*4 + lgrp)*136 + lrow*8]; } \
}while(0)

#define MM1(S) do{ \
    __builtin_amdgcn_s_setprio(1); \
    _Pragma("unroll") \
    for (int mf=0;mf<4;mf++) \
    _Pragma("unroll") \
    for (int nf=0;nf<4;nf++){ \
        acc[mf][nf] = __builtin_amdgcn_mfma_f32_16x16x32_bf16(fa##S[mf], fb##S##h[nf], acc[mf][nf],0,0,0); } \
    __builtin_amdgcn_s_setprio(0); \
}while(0)

    LDB(0, 0);
    #pragma unroll 1
    for (int kt = 0; kt < NT1; kt += 2){
        LDB(1, kt+1);
        LDA(0, kt);
        MM1(0);
        if (kt+2 < NT1) LDB(0, kt+2);
        LDA(1, kt+1);
        MM1(1);
    }
#undef LDB
#undef LDA
#undef MM1
    __syncthreads();                   // all waves done reading H

    // ---- epilogue 1: gelu(y + Dskip*xn) -> g_hi into LDS (aliases H) ----
    #pragma unroll
    for (int nf=0; nf<4; nf++){
        const int col = wv*64 + nf*16 + lrow;     // 0..255
        float dsk = d_skip[col], sc = ln_scale[col], bi = ln_bias[col];
        #pragma unroll
        for (int mf=0;mf<4;mf++){
            #pragma unroll
            for (int j=0;j<4;j++){
                int rl = mf*16 + lgrp*4 + j;
                int row = r0 + rl;
                size_t idx = (size_t)row*256 + col;
                float rs = rs_arr[row], muv = mu_arr[row];
                float xn = (x[idx] - muv)*rs*sc + bi;
                float g = gelu_tanh(acc[mf][nf][j] + dsk*xn);
                int o = (mf*32 + (col>>3))*128 + (lgrp*4+j)*8 + (col&7);
                Hbuf[o] = (short)bf16_rne(g);
            }
        }
    }
    __syncthreads();

    // ---- phase C: stage2 out = g_hi W_hi^T + b + x (1-product) ----
    #pragma unroll
    for (int mf=0;mf<4;mf++)
    #pragma unroll
    for (int nf=0;nf<4;nf++) acc[mf][nf] = (f32x4){0.f,0.f,0.f,0.f};

    const int b3base = ((wv*4)*32 + lgrp)*128 + lrow*8;
    #pragma unroll 1
    for (int kt = 0; kt < NT2; ++kt){
        const int ko = kt*512;
        bf16x8 bh[4], ah[4];
        #pragma unroll
        for (int nf=0;nf<4;nf++){
            bh[nf] = *(const bf16x8*)&B3hi[b3base + nf*KCS3 + ko];
        }
        #pragma unroll
        for (int mf=0;mf<4;mf++){
            const int o = (mf*32 + kt*4 + lgrp)*128 + lrow*8;
            ah[mf] = *(const bf16x8*)&Hbuf[o];
        }
        __builtin_amdgcn_s_setprio(1);
        #pragma unroll
        for (int mf=0;mf<4;mf++)
        #pragma unroll
        for (int nf=0;nf<4;nf++){
            acc[mf][nf] = __builtin_amdgcn_mfma_f32_16x16x32_bf16(ah[mf], bh[nf], acc[mf][nf],0,0,0);
        }
        __builtin_amdgcn_s_setprio(0);
    }

    #pragma unroll
    for (int nf=0; nf<4; nf++){
        const int col = wv*64 + nf*16 + lrow;
        float bb = bvec[col];
        #pragma unroll
        for (int mf=0;mf<4;mf++){
            #pragma unroll
            for (int j=0;j<4;j++){
                int row = r0 + mf*16 + lgrp*4 + j;
                size_t idx = (size_t)row*256 + col;
                out[idx] = acc[mf][nf][j] + bb + x[idx];
            }
        }
    }
}

// ---- scan kernels (chunk sums + fp64 combine) -------------------------------
__global__ __launch_bounds__(256)
void k_scan_local(const float* __restrict__ nu_log, const float* __restrict__ theta_log,
                  const float* __restrict__ bu_re, const float* __restrict__ bu_im,
                  float* __restrict__ e_re, float* __restrict__ e_im){
    int h = threadIdx.x;
    int bc = blockIdx.x;
    int b = bc / NC, c = bc % NC;
    float en = expf(nu_log[h]);
    float mag = expf(-en), th = expf(theta_log[h]);
    float lam_re = mag * cosf(th), lam_im = mag * sinf(th);
    int row0 = b*Lsz + c*CL;
    float sr = 0.f, si = 0.f;
    #pragma unroll 4
    for (int tt=0; tt<CL; tt++){
        int o = bu_dw(row0 + tt, h);
        float ur = bu_re[o], ui = bu_im[o];
        float nsr = fmaf(lam_re, sr, fmaf(-lam_im, si, ur));
        float nsi = fmaf(lam_re, si, fmaf( lam_im, sr, ui));
        sr = nsr; si = nsi;
    }
    e_re[(c*Bsz + b)*D + h] = sr;
    e_im[(c*Bsz + b)*D + h] = si;
}

__global__ __launch_bounds__(256)
void k_scan_combine(const float* __restrict__ nu_log, const float* __restrict__ theta_log,
                    const float* __restrict__ e_re, const float* __restrict__ e_im,
                    float* __restrict__ p_re, float* __restrict__ p_im){
    int h = threadIdx.x;
    int b = blockIdx.x;
    double en = exp((double)nu_log[h]);
    double th = exp((double)theta_log[h]);
    double mag = exp(-en);
    double lr = mag*cos(th), li = mag*sin(th);
    double ar = 1.0, ai = 0.0;               // lam^CL
    for (int i=0;i<CL;i++){
        double nr = ar*lr - ai*li;
        double ni = ar*li + ai*lr;
        ar = nr; ai = ni;
    }
    double sr = 0.0, si = 0.0;
    for (int c=0;c<NC;c++){
        int idx = (c*Bsz + b)*D + h;
        p_re[idx] = (float)sr; p_im[idx] = (float)si;
        double er = e_re[idx], ei = e_im[idx];
        double nr = ar*sr - ai*si + er;
        double ni = ar*si + ai*sr + ei;
        sr = nr; si = ni;
    }
}

extern "C" void kernel_launch(void* const* d_in, const int* in_sizes, int n_in,
                              void* d_out, int out_size, void* d_ws, size_t ws_size,
                              hipStream_t stream){
    const float* x         = (const float*)d_in[0];
    const float* ln_scale  = (const float*)d_in[1];
    const float* ln_bias   = (const float*)d_in[2];
    const float* nu_log    = (const float*)d_in[3];
    const float* theta_log = (const float*)d_in[4];
    const float* B_re      = (const float*)d_in[5];
    const float* B_im      = (const float*)d_in[6];
    const float* C_re      = (const float*)d_in[7];
    const float* C_im      = (const float*)d_in[8];
    const float* D_skip    = (const float*)d_in[9];
    const float* W         = (const float*)d_in[10];
    const float* bvec      = (const float*)d_in[11];
    float* out = (float*)d_out;

    char* base = (char*)d_ws;
    size_t off = 0;
    auto alloc = [&](size_t bytes)->char*{
        char* p = base + off;
        off += (bytes + 255) & ~(size_t)255;
        return p;
    };
    float*  bu_re = (float*)alloc((size_t)NROWS*D*4);
    float*  bu_im = (float*)alloc((size_t)NROWS*D*4);
    short*  xg_hi = (short*)alloc((size_t)NROWS*D*2);   // xhi (GEMM1 A)
    float*  mu_a  = (float*)alloc((size_t)NROWS*4);
    float*  rs_a  = (float*)alloc((size_t)NROWS*4);
    float*  e_re  = (float*)alloc((size_t)NC*Bsz*D*4);
    float*  e_im  = (float*)alloc((size_t)NC*Bsz*D*4);
    float*  p_re  = (float*)alloc((size_t)NC*Bsz*D*4);
    float*  p_im  = (float*)alloc((size_t)NC*Bsz*D*4);
    float*  t1    = (float*)alloc(512*4);
    float*  t2    = (float*)alloc(512*4);
    short*  b1_hi = (short*)alloc(512*256*2);
    short*  b2_hi = (short*)alloc(256*512*2);
    short*  b3_hi = (short*)alloc(256*256*2);

    k_prep<<<512, 256, 0, stream>>>(B_re, B_im, C_re, C_im, W, ln_scale,
                                    b1_hi, b2_hi, b3_hi);
    k_prep_t<<<2, 256, 0, stream>>>(B_re, B_im, ln_scale, ln_bias, t1, t2);
    k_stats<<<NROWS/16, 256, 0, stream>>>(x, mu_a, rs_a, xg_hi);

    // GEMM1: Bu = gamma*(LN(x) @ B1^T)   (N=512: cols 0-255 re, 256-511 im)
    k_gemm1<<<(NROWS/128)*4, 256, 0, stream>>>(
        xg_hi, b1_hi, mu_a, rs_a, t1, t2, nu_log, bu_re, bu_im);

    k_scan_local<<<Bsz*NC, 256, 0, stream>>>(nu_log, theta_log, bu_re, bu_im, e_re, e_im);
    k_scan_combine<<<Bsz, 256, 0, stream>>>(nu_log, theta_log, e_re, e_im, p_re, p_im);

    // fused scan + GEMM2 + GEMM3
    k_fuse_sgg<<<NROWS/64, 256, 0, stream>>>(
        bu_re, bu_im, p_re, p_im, nu_log, theta_log,
        b2_hi, b3_hi,
        x, mu_a, rs_a, ln_scale, ln_bias, D_skip, bvec, out);
}